// Round 4
// baseline (725.689 us; speedup 1.0000x reference)
//
#include <hip/hip_runtime.h>
#include <hip/hip_bf16.h>

#define HIDC 64
#define INC 128
#define OUTC 16
#define SCAN_CHUNK 1024
#define FILL_BLOCKS 1024
#define GEMM_BLOCKS 512

// ---------------- degree counting ----------------
__global__ __launch_bounds__(256) void count_deg(const int* __restrict__ dst,
                                                 int* __restrict__ cnt, int n_edges) {
    int e = blockIdx.x * 256 + threadIdx.x;
    if (e < n_edges) {
        int d = __builtin_nontemporal_load(dst + e);
        atomicAdd(&cnt[d], 1);
    }
}

// ---------------- hierarchical exclusive scan ----------------
__global__ __launch_bounds__(256) void scan_k1(const int* __restrict__ cnt,
                                               int* __restrict__ partial, int n) {
    int base = blockIdx.x * SCAN_CHUNK;
    int lim = min(base + SCAN_CHUNK, n);
    int s = 0;
    for (int i = base + threadIdx.x; i < lim; i += 256) s += cnt[i];
    #pragma unroll
    for (int d = 32; d; d >>= 1) s += __shfl_down(s, d);
    __shared__ int wsum[4];
    if ((threadIdx.x & 63) == 0) wsum[threadIdx.x >> 6] = s;
    __syncthreads();
    if (threadIdx.x == 0) partial[blockIdx.x] = wsum[0] + wsum[1] + wsum[2] + wsum[3];
}

__global__ __launch_bounds__(256) void scan_k2(const int* __restrict__ partial,
                                               int* __restrict__ pbase,
                                               int* __restrict__ off, int nblk, int n) {
    __shared__ int sh[256];
    int v = (threadIdx.x < nblk) ? partial[threadIdx.x] : 0;
    sh[threadIdx.x] = v;
    __syncthreads();
    for (int d = 1; d < 256; d <<= 1) {
        int t = (threadIdx.x >= d) ? sh[threadIdx.x - d] : 0;
        __syncthreads();
        sh[threadIdx.x] += t;
        __syncthreads();
    }
    if (threadIdx.x < nblk) pbase[threadIdx.x] = sh[threadIdx.x] - v;
    if (threadIdx.x == nblk - 1) off[n] = sh[threadIdx.x];
}

// scan_k3 also produces dis = rsqrt(cnt+1) (finish_dis folded in)
__global__ __launch_bounds__(256) void scan_k3(const int* __restrict__ cnt,
                                               const int* __restrict__ pbase,
                                               int* __restrict__ off,
                                               int* __restrict__ cur,
                                               float* __restrict__ dis, int n) {
    int i0 = blockIdx.x * SCAN_CHUNK + threadIdx.x * 4;
    int c0 = 0, c1 = 0, c2 = 0, c3 = 0;
    if (i0 + 3 < n) {
        int4 t = *(const int4*)(cnt + i0);
        c0 = t.x; c1 = t.y; c2 = t.z; c3 = t.w;
    } else {
        if (i0 + 0 < n) c0 = cnt[i0 + 0];
        if (i0 + 1 < n) c1 = cnt[i0 + 1];
        if (i0 + 2 < n) c2 = cnt[i0 + 2];
        if (i0 + 3 < n) c3 = cnt[i0 + 3];
    }
    int tsum = c0 + c1 + c2 + c3;
    __shared__ int sh[256];
    sh[threadIdx.x] = tsum;
    __syncthreads();
    for (int d = 1; d < 256; d <<= 1) {
        int t = (threadIdx.x >= d) ? sh[threadIdx.x - d] : 0;
        __syncthreads();
        sh[threadIdx.x] += t;
        __syncthreads();
    }
    int pre = pbase[blockIdx.x] + sh[threadIdx.x] - tsum;
    int o0 = pre, o1 = pre + c0, o2 = o1 + c1, o3 = o2 + c2;
    if (i0 + 3 < n) {
        *(int4*)(off + i0) = make_int4(o0, o1, o2, o3);
        *(int4*)(cur + i0) = make_int4(o0, o1, o2, o3);
        float4 dv = make_float4(rsqrtf((float)(c0 + 1)), rsqrtf((float)(c1 + 1)),
                                rsqrtf((float)(c2 + 1)), rsqrtf((float)(c3 + 1)));
        *(float4*)(dis + i0) = dv;
    } else {
        if (i0 + 0 < n) { off[i0 + 0] = o0; cur[i0 + 0] = o0; dis[i0 + 0] = rsqrtf((float)(c0 + 1)); }
        if (i0 + 1 < n) { off[i0 + 1] = o1; cur[i0 + 1] = o1; dis[i0 + 1] = rsqrtf((float)(c1 + 1)); }
        if (i0 + 2 < n) { off[i0 + 2] = o2; cur[i0 + 2] = o2; dis[i0 + 2] = rsqrtf((float)(c2 + 1)); }
        if (i0 + 3 < n) { off[i0 + 3] = o3; cur[i0 + 3] = o3; dis[i0 + 3] = rsqrtf((float)(c3 + 1)); }
    }
}

// ---------------- fused: XCD-partitioned CSR fill + GEMM1 ----------------
// blocks [0, FILL_BLOCKS): fill role. blockIdx%8 = disjoint dst range
// (heuristically one XCD). nt loads keep the edge stream out of L2 so the
// csr window + cursors stay resident -> full-line writebacks.
// blocks [FILL_BLOCKS, FILL_BLOCKS+GEMM_BLOCKS): xW = x @ W1.
// Correct for any block->XCD mapping (ranges disjoint; roles by blockIdx).
__global__ __launch_bounds__(256) void fill_gemm(const int* __restrict__ src,
                                                 const int* __restrict__ dst,
                                                 int* __restrict__ cur,
                                                 int* __restrict__ csr,
                                                 int n_edges, int nodes_per_part,
                                                 const float* __restrict__ x,
                                                 const float* __restrict__ W,
                                                 float* __restrict__ xW, int n_nodes) {
    __shared__ float Wl[INC * HIDC];   // 32 KB (reserved for both roles)
    __shared__ float xr[4][INC];
    if (blockIdx.x < FILL_BLOCKS) {
        const int part = blockIdx.x & 7;
        const int lo = part * nodes_per_part;
        const int hi = min(lo + nodes_per_part, n_nodes);
        const int nblk = FILL_BLOCKS >> 3;
        const int bid = blockIdx.x >> 3;
        for (int e = bid * 256 + threadIdx.x; e < n_edges; e += nblk * 256) {
            int d = __builtin_nontemporal_load(dst + e);
            if (d >= lo && d < hi) {
                int s = __builtin_nontemporal_load(src + e);
                int slot = atomicAdd(&cur[d], 1);
                csr[slot] = s;
            }
        }
    } else {
        const int gb = blockIdx.x - FILL_BLOCKS;
        for (int i = threadIdx.x; i < INC * HIDC; i += 256) Wl[i] = W[i];
        const int wid = threadIdx.x >> 6, lane = threadIdx.x & 63;
        for (int base = gb * 4; base < n_nodes; base += GEMM_BLOCKS * 4) {
            int nrows = min(4, n_nodes - base);
            __syncthreads();
            for (int i = threadIdx.x; i < nrows * (INC / 4); i += 256)
                ((float4*)xr)[i] = ((const float4*)(x + (size_t)base * INC))[i];
            __syncthreads();
            if (wid < nrows) {
                float acc = 0.f;
                #pragma unroll
                for (int k = 0; k < INC; ++k) acc += xr[wid][k] * Wl[k * HIDC + lane];
                xW[(size_t)(base + wid) * HIDC + lane] = acc;
            }
        }
    }
}

// ---------------- GEMM 2: hw = h @ [W_mu | W_ls] ----------------
__global__ __launch_bounds__(256) void gemm_h_w(const float* __restrict__ h,
                                                const float* __restrict__ Wmu,
                                                const float* __restrict__ Wls,
                                                float* __restrict__ out, int n_nodes) {
    __shared__ float Wl[HIDC * 32];
    __shared__ float hr[8][HIDC];
    for (int i = threadIdx.x; i < HIDC * OUTC; i += 256) {
        int k = i >> 4, c = i & 15;
        Wl[k * 32 + c]      = Wmu[i];
        Wl[k * 32 + 16 + c] = Wls[i];
    }
    const int wid = threadIdx.x >> 6, lane = threadIdx.x & 63;
    const int sub = lane >> 5, ch = lane & 31;
    for (int base = blockIdx.x * 8; base < n_nodes; base += gridDim.x * 8) {
        int nrows = min(8, n_nodes - base);
        __syncthreads();
        for (int i = threadIdx.x; i < nrows * (HIDC / 4); i += 256)
            ((float4*)hr)[i] = ((const float4*)(h + (size_t)base * HIDC))[i];
        __syncthreads();
        int n = wid * 2 + sub;
        if (n < nrows) {
            float acc = 0.f;
            #pragma unroll
            for (int k = 0; k < HIDC; ++k) acc += hr[n][k] * Wl[k * 32 + ch];
            out[(size_t)(base + n) * 32 + ch] = acc;
        }
    }
}

// ---------------- gather conv1: float4, 4 edges in flight per wave ----------
__global__ __launch_bounds__(256) void gather64(const float4* __restrict__ xW4,
                                                float4* __restrict__ h4,
                                                const int* __restrict__ csr,
                                                const int* __restrict__ off,
                                                const float* __restrict__ dis,
                                                const float* __restrict__ b1,
                                                int n_nodes) {
    int node = (blockIdx.x * 256 + threadIdx.x) >> 6;
    int lane = threadIdx.x & 63;
    if (node >= n_nodes) return;
    const int beg = off[node], end = off[node + 1];
    const float dn = dis[node];
    const int sub = lane >> 4;
    const int c4  = lane & 15;
    float4 acc = {0.f, 0.f, 0.f, 0.f};
    for (int base = beg; base < end; base += 64) {
        const int cnt = min(64, end - base);
        int s = 0; float nrm = 0.f;
        if (lane < cnt) {
            s = __builtin_nontemporal_load(csr + base + lane);
            nrm = dis[s] * dn;
        }
        for (int j = 0; j < cnt; j += 4) {
            int jj = j + sub;
            int sj = __shfl(s, jj);
            float nj = __shfl(nrm, jj);
            if (jj < cnt) {
                float4 r = xW4[(size_t)sj * 16 + c4];
                acc.x += r.x * nj; acc.y += r.y * nj;
                acc.z += r.z * nj; acc.w += r.w * nj;
            }
        }
    }
    acc.x += __shfl_xor(acc.x, 16); acc.y += __shfl_xor(acc.y, 16);
    acc.z += __shfl_xor(acc.z, 16); acc.w += __shfl_xor(acc.w, 16);
    acc.x += __shfl_xor(acc.x, 32); acc.y += __shfl_xor(acc.y, 32);
    acc.z += __shfl_xor(acc.z, 32); acc.w += __shfl_xor(acc.w, 32);
    if (sub == 0) {
        float4 self = xW4[(size_t)node * 16 + c4];
        float s2 = dn * dn;
        float4 b = ((const float4*)b1)[c4];
        float4 o;
        o.x = fmaxf(acc.x + self.x * s2 + b.x, 0.f);
        o.y = fmaxf(acc.y + self.y * s2 + b.y, 0.f);
        o.z = fmaxf(acc.z + self.z * s2 + b.z, 0.f);
        o.w = fmaxf(acc.w + self.w * s2 + b.w, 0.f);
        h4[(size_t)node * 16 + c4] = o;
    }
}

// ---------------- gather conv2: float4, 8 edges in flight per wave ----------
__global__ __launch_bounds__(256) void gather32(const float4* __restrict__ hw4,
                                                const int* __restrict__ csr,
                                                const int* __restrict__ off,
                                                const float* __restrict__ dis,
                                                const float* __restrict__ bmu,
                                                const float* __restrict__ bls,
                                                float* __restrict__ out,
                                                int n_nodes) {
    int node = (blockIdx.x * 256 + threadIdx.x) >> 6;
    int lane = threadIdx.x & 63;
    if (node >= n_nodes) return;
    const int beg = off[node], end = off[node + 1];
    const float dn = dis[node];
    const int sub = lane >> 3;
    const int c4  = lane & 7;
    float4 acc = {0.f, 0.f, 0.f, 0.f};
    for (int base = beg; base < end; base += 64) {
        const int cnt = min(64, end - base);
        int s = 0; float nrm = 0.f;
        if (lane < cnt) {
            s = __builtin_nontemporal_load(csr + base + lane);
            nrm = dis[s] * dn;
        }
        for (int j = 0; j < cnt; j += 8) {
            int jj = j + sub;
            int sj = __shfl(s, jj);
            float nj = __shfl(nrm, jj);
            if (jj < cnt) {
                float4 r = hw4[(size_t)sj * 8 + c4];
                acc.x += r.x * nj; acc.y += r.y * nj;
                acc.z += r.z * nj; acc.w += r.w * nj;
            }
        }
    }
    acc.x += __shfl_xor(acc.x, 8);  acc.y += __shfl_xor(acc.y, 8);
    acc.z += __shfl_xor(acc.z, 8);  acc.w += __shfl_xor(acc.w, 8);
    acc.x += __shfl_xor(acc.x, 16); acc.y += __shfl_xor(acc.y, 16);
    acc.z += __shfl_xor(acc.z, 16); acc.w += __shfl_xor(acc.w, 16);
    acc.x += __shfl_xor(acc.x, 32); acc.y += __shfl_xor(acc.y, 32);
    acc.z += __shfl_xor(acc.z, 32); acc.w += __shfl_xor(acc.w, 32);
    if (sub == 0) {
        float4 self = hw4[(size_t)node * 8 + c4];
        float s2 = dn * dn;
        float4 b = (c4 < 4) ? ((const float4*)bmu)[c4] : ((const float4*)bls)[c4 - 4];
        float4 o;
        o.x = acc.x + self.x * s2 + b.x;
        o.y = acc.y + self.y * s2 + b.y;
        o.z = acc.z + self.z * s2 + b.z;
        o.w = acc.w + self.w * s2 + b.w;
        if (c4 < 4)
            ((float4*)out)[(size_t)node * 4 + c4] = o;
        else
            ((float4*)out)[((size_t)n_nodes + node) * 4 + (c4 - 4)] = o;
    }
}

extern "C" void kernel_launch(void* const* d_in, const int* in_sizes, int n_in,
                              void* d_out, int out_size, void* d_ws, size_t ws_size,
                              hipStream_t stream) {
    const float* x   = (const float*)d_in[0];
    const int*   ei  = (const int*)d_in[1];
    const float* W1  = (const float*)d_in[2];
    const float* b1  = (const float*)d_in[3];
    const float* Wmu = (const float*)d_in[4];
    const float* bmu = (const float*)d_in[5];
    const float* Wls = (const float*)d_in[6];
    const float* bls = (const float*)d_in[7];
    float* out = (float*)d_out;

    const int N = in_sizes[0] / INC;
    const int E = in_sizes[1] / 2;
    const int* src = ei;
    const int* dst = ei + E;

    // workspace (4-byte words):
    //   dis [0,131072) | cnt/cursor [131072,262144) | off [262144,393216)
    //   csr [393216, 393216+E) | xW next N*64 | h next N*64 ; hw aliases xW
    float* ws  = (float*)d_ws;
    float* dis = ws;
    int*   cnt = (int*)(ws + 131072);            // doubles as cursor
    int*   off = (int*)(ws + 262144);
    int*   csr = (int*)(ws + 393216);
    float* xW  = ws + 393216 + (size_t)E;
    float* h   = xW + (size_t)N * HIDC;
    float* hw  = xW;                              // xW dead after gather64
    int*   partial = cnt + 100352;
    int*   pbase   = cnt + 100608;

    const int EB = (E + 255) / 256;
    const int SB = (N + SCAN_CHUNK - 1) / SCAN_CHUNK;  // <=256

    hipMemsetAsync(cnt, 0, (size_t)N * sizeof(int), stream);
    count_deg<<<EB, 256, 0, stream>>>(dst, cnt, E);

    scan_k1<<<SB, 256, 0, stream>>>(cnt, partial, N);
    scan_k2<<<1, 256, 0, stream>>>(partial, pbase, off, SB, N);
    scan_k3<<<SB, 256, 0, stream>>>(cnt, pbase, off, cnt /*cursor*/, dis, N);

    fill_gemm<<<FILL_BLOCKS + GEMM_BLOCKS, 256, 0, stream>>>(
        src, dst, cnt, csr, E, (N + 7) / 8, x, W1, xW, N);

    gather64<<<(N * 64 + 255) / 256, 256, 0, stream>>>((const float4*)xW, (float4*)h,
                                                       csr, off, dis, b1, N);

    gemm_h_w<<<1024, 256, 0, stream>>>(h, Wmu, Wls, hw, N);
    gather32<<<(N * 64 + 255) / 256, 256, 0, stream>>>((const float4*)hw, csr, off, dis,
                                                       bmu, bls, out, N);
}

// Round 5
// 671.003 us; speedup vs baseline: 1.0815x; 1.0815x over previous
//
#include <hip/hip_runtime.h>
#include <hip/hip_bf16.h>

#define HIDC 64
#define INC 128
#define OUTC 16
#define CAP 16          // LDS staging depth per bucket
#define BIN_BLOCKS 512

// ---------------- pass 0: coarse bucket histogram (bucket = dst>>9) --------
__global__ __launch_bounds__(256) void hist_bucket(const int* __restrict__ dst,
                                                   int* __restrict__ gbh,
                                                   int n_edges, int nbuck) {
    __shared__ int lh[256];
    lh[threadIdx.x] = 0;
    __syncthreads();
    int stride = gridDim.x * 256;
    for (int e = blockIdx.x * 256 + threadIdx.x; e < n_edges; e += stride) {
        int d = __builtin_nontemporal_load(dst + e);
        atomicAdd(&lh[d >> 9], 1);
    }
    __syncthreads();
    if (threadIdx.x < nbuck) atomicAdd(&gbh[threadIdx.x], lh[threadIdx.x]);
}

// ---------------- pass 0b: scan bucket totals -> bo, gcur; off[N]=E --------
__global__ __launch_bounds__(256) void scan_bucket(const int* __restrict__ gbh,
                                                   int* __restrict__ bo,
                                                   int* __restrict__ gcur,
                                                   int* __restrict__ off,
                                                   int nbuck, int n_nodes, int n_edges) {
    __shared__ int ss[256];
    int v = (threadIdx.x < nbuck) ? gbh[threadIdx.x] : 0;
    ss[threadIdx.x] = v;
    __syncthreads();
    for (int d = 1; d < 256; d <<= 1) {
        int t = (threadIdx.x >= d) ? ss[threadIdx.x - d] : 0;
        __syncthreads();
        ss[threadIdx.x] += t;
        __syncthreads();
    }
    int ex = ss[threadIdx.x] - v;
    if (threadIdx.x < nbuck) { bo[threadIdx.x] = ex; gcur[threadIdx.x] = ex; }
    if (threadIdx.x == nbuck - 1) bo[nbuck] = ss[threadIdx.x];   // = E
    if (threadIdx.x == 0) off[n_nodes] = n_edges;
}

// ---------------- pass 1: LDS-staged binning of packed (d_local,s) ---------
// pack: v = s | ((d & 511) << 17)   (requires N <= 131072)
// Stage layout stage[pos][bucket]: store bank = bucket&31 (uniform, random b).
// Flush full groups of 8 as contiguous dword bursts -> write-amp ~1.
__global__ __launch_bounds__(256) void bin_pairs(const int* __restrict__ src,
                                                 const int* __restrict__ dst,
                                                 int* __restrict__ gcur,
                                                 int* __restrict__ pairs,
                                                 int n_edges, int nbuck) {
    __shared__ int lcnt[256];
    __shared__ int stage[CAP][256];   // 16 KB
    lcnt[threadIdx.x] = 0;
    __syncthreads();
    const int chunk = (n_edges + BIN_BLOCKS - 1) / BIN_BLOCKS;
    const int begin = blockIdx.x * chunk;
    const int end = min(begin + chunk, n_edges);
    for (int tb = begin; tb < end; tb += 256) {
        int e = tb + threadIdx.x;
        if (e < end) {
            int d = __builtin_nontemporal_load(dst + e);
            int s = __builtin_nontemporal_load(src + e);
            int b = d >> 9;
            int v = s | ((d & 511) << 17);
            int pos = atomicAdd(&lcnt[b], 1);
            if (pos < CAP) {
                stage[pos][b] = v;
            } else {
                // rare overflow: direct global placement (correct, slower)
                int slot = atomicAdd(&gcur[b], 1);
                pairs[slot] = v;
            }
        }
        __syncthreads();
        if (threadIdx.x < nbuck) {
            int held = min(lcnt[threadIdx.x], CAP);
            int nf = held & ~7;           // multiple of 8
            if (nf > 0) {
                int gbase = atomicAdd(&gcur[threadIdx.x], nf);
                for (int i = 0; i < nf; ++i)
                    pairs[gbase + i] = stage[i][threadIdx.x];
                int rem = held - nf;
                for (int i = 0; i < rem; ++i)
                    stage[i][threadIdx.x] = stage[nf + i][threadIdx.x];
                lcnt[threadIdx.x] = rem;
            } else {
                lcnt[threadIdx.x] = held;  // clamp any overflowed count
            }
        }
        __syncthreads();
    }
    // drain remainders (<8 per bucket per block)
    if (threadIdx.x < nbuck) {
        int n = min(lcnt[threadIdx.x], CAP);
        if (n > 0) {
            int gbase = atomicAdd(&gcur[threadIdx.x], n);
            for (int i = 0; i < n; ++i)
                pairs[gbase + i] = stage[i][threadIdx.x];
        }
    }
}

// ---------------- pass 2: per-bucket CSR build + off + dis -----------------
// One block per bucket. All scatter writes land in the bucket's contiguous
// csr window (<=65 KB, L2-resident) -> full-line writebacks.
__global__ __launch_bounds__(256) void csr_bucket(const int* __restrict__ pairs,
                                                  const int* __restrict__ bo,
                                                  int* __restrict__ off,
                                                  float* __restrict__ dis,
                                                  int* __restrict__ csr,
                                                  int n_nodes) {
    __shared__ int hist[512];
    __shared__ int lofs[512];
    __shared__ int ss[256];
    const int b = blockIdx.x;
    const int node0 = b << 9;
    const int nn = min(512, n_nodes - node0);
    const int pbeg = bo[b], pend = bo[b + 1];
    const int tid = threadIdx.x;
    if (2 * tid < nn) hist[2 * tid] = 0;
    if (2 * tid + 1 < nn) hist[2 * tid + 1] = 0;
    __syncthreads();
    for (int i = pbeg + tid; i < pend; i += 256)
        atomicAdd(&hist[pairs[i] >> 17], 1);
    __syncthreads();
    int h0 = (2 * tid < nn) ? hist[2 * tid] : 0;
    int h1 = (2 * tid + 1 < nn) ? hist[2 * tid + 1] : 0;
    ss[tid] = h0 + h1;
    __syncthreads();
    for (int d = 1; d < 256; d <<= 1) {
        int t = (tid >= d) ? ss[tid - d] : 0;
        __syncthreads();
        ss[tid] += t;
        __syncthreads();
    }
    int pre = pbeg + ss[tid] - (h0 + h1);   // exclusive, global edge index
    if (2 * tid < nn) {
        lofs[2 * tid] = pre;
        off[node0 + 2 * tid] = pre;
        dis[node0 + 2 * tid] = rsqrtf((float)(h0 + 1));
    }
    if (2 * tid + 1 < nn) {
        lofs[2 * tid + 1] = pre + h0;
        off[node0 + 2 * tid + 1] = pre + h0;
        dis[node0 + 2 * tid + 1] = rsqrtf((float)(h1 + 1));
    }
    __syncthreads();
    for (int i = pbeg + tid; i < pend; i += 256) {
        int v = pairs[i];
        int slot = atomicAdd(&lofs[v >> 17], 1);
        csr[slot] = v & 0x1FFFF;
    }
}

// ---------------- GEMM 1: xW = x @ W1 ----------------
__global__ __launch_bounds__(256) void gemm_x_w(const float* __restrict__ x,
                                                const float* __restrict__ W,
                                                float* __restrict__ out, int n_nodes) {
    __shared__ float Wl[INC * HIDC];
    __shared__ float xr[4][INC];
    for (int i = threadIdx.x; i < INC * HIDC; i += 256) Wl[i] = W[i];
    const int wid = threadIdx.x >> 6, lane = threadIdx.x & 63;
    for (int base = blockIdx.x * 4; base < n_nodes; base += gridDim.x * 4) {
        int nrows = min(4, n_nodes - base);
        __syncthreads();
        for (int i = threadIdx.x; i < nrows * (INC / 4); i += 256)
            ((float4*)xr)[i] = ((const float4*)(x + (size_t)base * INC))[i];
        __syncthreads();
        if (wid < nrows) {
            float acc = 0.f;
            #pragma unroll
            for (int k = 0; k < INC; ++k) acc += xr[wid][k] * Wl[k * HIDC + lane];
            out[(size_t)(base + wid) * HIDC + lane] = acc;
        }
    }
}

// ---------------- GEMM 2: hw = h @ [W_mu | W_ls] ----------------
__global__ __launch_bounds__(256) void gemm_h_w(const float* __restrict__ h,
                                                const float* __restrict__ Wmu,
                                                const float* __restrict__ Wls,
                                                float* __restrict__ out, int n_nodes) {
    __shared__ float Wl[HIDC * 32];
    __shared__ float hr[8][HIDC];
    for (int i = threadIdx.x; i < HIDC * OUTC; i += 256) {
        int k = i >> 4, c = i & 15;
        Wl[k * 32 + c]      = Wmu[i];
        Wl[k * 32 + 16 + c] = Wls[i];
    }
    const int wid = threadIdx.x >> 6, lane = threadIdx.x & 63;
    const int sub = lane >> 5, ch = lane & 31;
    for (int base = blockIdx.x * 8; base < n_nodes; base += gridDim.x * 8) {
        int nrows = min(8, n_nodes - base);
        __syncthreads();
        for (int i = threadIdx.x; i < nrows * (HIDC / 4); i += 256)
            ((float4*)hr)[i] = ((const float4*)(h + (size_t)base * HIDC))[i];
        __syncthreads();
        int n = wid * 2 + sub;
        if (n < nrows) {
            float acc = 0.f;
            #pragma unroll
            for (int k = 0; k < HIDC; ++k) acc += hr[n][k] * Wl[k * 32 + ch];
            out[(size_t)(base + n) * 32 + ch] = acc;
        }
    }
}

// ---------------- gather conv1: float4, 4 edges in flight per wave ----------
__global__ __launch_bounds__(256) void gather64(const float4* __restrict__ xW4,
                                                float4* __restrict__ h4,
                                                const int* __restrict__ csr,
                                                const int* __restrict__ off,
                                                const float* __restrict__ dis,
                                                const float* __restrict__ b1,
                                                int n_nodes) {
    int node = (blockIdx.x * 256 + threadIdx.x) >> 6;
    int lane = threadIdx.x & 63;
    if (node >= n_nodes) return;
    const int beg = off[node], end = off[node + 1];
    const float dn = dis[node];
    const int sub = lane >> 4;
    const int c4  = lane & 15;
    float4 acc = {0.f, 0.f, 0.f, 0.f};
    for (int base = beg; base < end; base += 64) {
        const int cnt = min(64, end - base);
        int s = 0; float nrm = 0.f;
        if (lane < cnt) {
            s = __builtin_nontemporal_load(csr + base + lane);
            nrm = dis[s] * dn;
        }
        for (int j = 0; j < cnt; j += 4) {
            int jj = j + sub;
            int sj = __shfl(s, jj);
            float nj = __shfl(nrm, jj);
            if (jj < cnt) {
                float4 r = xW4[(size_t)sj * 16 + c4];
                acc.x += r.x * nj; acc.y += r.y * nj;
                acc.z += r.z * nj; acc.w += r.w * nj;
            }
        }
    }
    acc.x += __shfl_xor(acc.x, 16); acc.y += __shfl_xor(acc.y, 16);
    acc.z += __shfl_xor(acc.z, 16); acc.w += __shfl_xor(acc.w, 16);
    acc.x += __shfl_xor(acc.x, 32); acc.y += __shfl_xor(acc.y, 32);
    acc.z += __shfl_xor(acc.z, 32); acc.w += __shfl_xor(acc.w, 32);
    if (sub == 0) {
        float4 self = xW4[(size_t)node * 16 + c4];
        float s2 = dn * dn;
        float4 b = ((const float4*)b1)[c4];
        float4 o;
        o.x = fmaxf(acc.x + self.x * s2 + b.x, 0.f);
        o.y = fmaxf(acc.y + self.y * s2 + b.y, 0.f);
        o.z = fmaxf(acc.z + self.z * s2 + b.z, 0.f);
        o.w = fmaxf(acc.w + self.w * s2 + b.w, 0.f);
        h4[(size_t)node * 16 + c4] = o;
    }
}

// ---------------- gather conv2: float4, 8 edges in flight per wave ----------
__global__ __launch_bounds__(256) void gather32(const float4* __restrict__ hw4,
                                                const int* __restrict__ csr,
                                                const int* __restrict__ off,
                                                const float* __restrict__ dis,
                                                const float* __restrict__ bmu,
                                                const float* __restrict__ bls,
                                                float* __restrict__ out,
                                                int n_nodes) {
    int node = (blockIdx.x * 256 + threadIdx.x) >> 6;
    int lane = threadIdx.x & 63;
    if (node >= n_nodes) return;
    const int beg = off[node], end = off[node + 1];
    const float dn = dis[node];
    const int sub = lane >> 3;
    const int c4  = lane & 7;
    float4 acc = {0.f, 0.f, 0.f, 0.f};
    for (int base = beg; base < end; base += 64) {
        const int cnt = min(64, end - base);
        int s = 0; float nrm = 0.f;
        if (lane < cnt) {
            s = __builtin_nontemporal_load(csr + base + lane);
            nrm = dis[s] * dn;
        }
        for (int j = 0; j < cnt; j += 8) {
            int jj = j + sub;
            int sj = __shfl(s, jj);
            float nj = __shfl(nrm, jj);
            if (jj < cnt) {
                float4 r = hw4[(size_t)sj * 8 + c4];
                acc.x += r.x * nj; acc.y += r.y * nj;
                acc.z += r.z * nj; acc.w += r.w * nj;
            }
        }
    }
    acc.x += __shfl_xor(acc.x, 8);  acc.y += __shfl_xor(acc.y, 8);
    acc.z += __shfl_xor(acc.z, 8);  acc.w += __shfl_xor(acc.w, 8);
    acc.x += __shfl_xor(acc.x, 16); acc.y += __shfl_xor(acc.y, 16);
    acc.z += __shfl_xor(acc.z, 16); acc.w += __shfl_xor(acc.w, 16);
    acc.x += __shfl_xor(acc.x, 32); acc.y += __shfl_xor(acc.y, 32);
    acc.z += __shfl_xor(acc.z, 32); acc.w += __shfl_xor(acc.w, 32);
    if (sub == 0) {
        float4 self = hw4[(size_t)node * 8 + c4];
        float s2 = dn * dn;
        float4 b = (c4 < 4) ? ((const float4*)bmu)[c4] : ((const float4*)bls)[c4 - 4];
        float4 o;
        o.x = acc.x + self.x * s2 + b.x;
        o.y = acc.y + self.y * s2 + b.y;
        o.z = acc.z + self.z * s2 + b.z;
        o.w = acc.w + self.w * s2 + b.w;
        if (c4 < 4)
            ((float4*)out)[(size_t)node * 4 + c4] = o;
        else
            ((float4*)out)[((size_t)n_nodes + node) * 4 + (c4 - 4)] = o;
    }
}

extern "C" void kernel_launch(void* const* d_in, const int* in_sizes, int n_in,
                              void* d_out, int out_size, void* d_ws, size_t ws_size,
                              hipStream_t stream) {
    const float* x   = (const float*)d_in[0];
    const int*   ei  = (const int*)d_in[1];
    const float* W1  = (const float*)d_in[2];
    const float* b1  = (const float*)d_in[3];
    const float* Wmu = (const float*)d_in[4];
    const float* bmu = (const float*)d_in[5];
    const float* Wls = (const float*)d_in[6];
    const float* bls = (const float*)d_in[7];
    float* out = (float*)d_out;

    const int N = in_sizes[0] / INC;       // 100000  (packing needs N<=131072)
    const int E = in_sizes[1] / 2;         // 3200000
    const int* src = ei;
    const int* dst = ei + E;
    const int NBUCK = (N + 511) >> 9;      // 196 (<=256 required)

    // workspace (4-byte words):
    //   dis [0,131072) | off [131072,262144) | bh/bo/gcur [262144,263168)
    //   csr [393216, 393216+E) | xW next 64N | h next 64N (pairs aliases h)
    float* ws  = (float*)d_ws;
    float* dis = ws;
    int*   off = (int*)(ws + 131072);
    int*   bh  = (int*)(ws + 262144);
    int*   bo  = (int*)(ws + 262400);
    int*   gcur= (int*)(ws + 262656);
    int*   csr = (int*)(ws + 393216);
    float* xW  = ws + 393216 + (size_t)E;
    float* h   = xW + (size_t)N * HIDC;
    int*   pairs = (int*)h;                // dead once csr built (before gather64)
    float* hw  = xW;                       // xW dead after gather64

    hipMemsetAsync(bh, 0, 256 * sizeof(int), stream);
    hist_bucket<<<256, 256, 0, stream>>>(dst, bh, E, NBUCK);
    scan_bucket<<<1, 256, 0, stream>>>(bh, bo, gcur, off, NBUCK, N, E);
    bin_pairs<<<BIN_BLOCKS, 256, 0, stream>>>(src, dst, gcur, pairs, E, NBUCK);
    csr_bucket<<<NBUCK, 256, 0, stream>>>(pairs, bo, off, dis, csr, N);

    gemm_x_w<<<1024, 256, 0, stream>>>(x, W1, xW, N);
    gather64<<<(N * 64 + 255) / 256, 256, 0, stream>>>((const float4*)xW, (float4*)h,
                                                       csr, off, dis, b1, N);

    gemm_h_w<<<1024, 256, 0, stream>>>(h, Wmu, Wls, hw, N);
    gather32<<<(N * 64 + 255) / 256, 256, 0, stream>>>((const float4*)hw, csr, off, dis,
                                                       bmu, bls, out, N);
}

// Round 6
// 479.496 us; speedup vs baseline: 1.5134x; 1.3994x over previous
//
#include <hip/hip_runtime.h>
#include <hip/hip_bf16.h>

#define HIDC 64
#define INC 128
#define OUTC 16
#define NBLK 512            // blocks in count/place passes (must be pow2)
#define BSHIFT 8            // bucket = 256 nodes
#define MAXBUCK 512         // LDS array bound (nbuck=391 for N=100k)

// ---------------- pass A: per-(block,bucket) counts, no global atomics -----
__global__ __launch_bounds__(256) void count_pass(const int* __restrict__ dst,
                                                  int* __restrict__ bcnt,
                                                  int n_edges, int nbuck) {
    __shared__ int lh[MAXBUCK];
    for (int i = threadIdx.x; i < nbuck; i += 256) lh[i] = 0;
    __syncthreads();
    const int chunk = (n_edges + NBLK - 1) / NBLK;
    const int begin = blockIdx.x * chunk;
    const int end = min(begin + chunk, n_edges);
    for (int e = begin + threadIdx.x; e < end; e += 256) {
        int d = __builtin_nontemporal_load(dst + e);
        atomicAdd(&lh[d >> BSHIFT], 1);
    }
    __syncthreads();
    for (int i = threadIdx.x; i < nbuck; i += 256)
        bcnt[blockIdx.x * nbuck + i] = lh[i];
}

// ---------------- scan of the count matrix in bucket-major logical order ---
// logical j = bucket*NBLK + blk  ->  physical p = blk*nbuck + bucket
__device__ __forceinline__ int xphys(int j, int nbuck) {
    return (j & (NBLK - 1)) * nbuck + (j >> 9);
}

__global__ __launch_bounds__(256) void mscan_k1(const int* __restrict__ bcnt,
                                                int* __restrict__ partial,
                                                int m, int nbuck) {
    int base = blockIdx.x * 1024;
    int lim = min(base + 1024, m);
    int s = 0;
    for (int j = base + threadIdx.x; j < lim; j += 256) s += bcnt[xphys(j, nbuck)];
    #pragma unroll
    for (int d = 32; d; d >>= 1) s += __shfl_down(s, d);
    __shared__ int wsum[4];
    if ((threadIdx.x & 63) == 0) wsum[threadIdx.x >> 6] = s;
    __syncthreads();
    if (threadIdx.x == 0) partial[blockIdx.x] = wsum[0] + wsum[1] + wsum[2] + wsum[3];
}

__global__ __launch_bounds__(256) void mscan_k2(const int* __restrict__ partial,
                                                int* __restrict__ pbase, int nblk) {
    __shared__ int sh[256];
    int v = (threadIdx.x < nblk) ? partial[threadIdx.x] : 0;
    sh[threadIdx.x] = v;
    __syncthreads();
    for (int d = 1; d < 256; d <<= 1) {
        int t = (threadIdx.x >= d) ? sh[threadIdx.x - d] : 0;
        __syncthreads();
        sh[threadIdx.x] += t;
        __syncthreads();
    }
    if (threadIdx.x < nblk) pbase[threadIdx.x] = sh[threadIdx.x] - v;
}

__global__ __launch_bounds__(256) void mscan_k3(const int* __restrict__ bcnt,
                                                const int* __restrict__ pbase,
                                                int* __restrict__ bofs,
                                                int m, int nbuck) {
    int j0 = blockIdx.x * 1024 + threadIdx.x * 4;
    int c0 = (j0 + 0 < m) ? bcnt[xphys(j0 + 0, nbuck)] : 0;
    int c1 = (j0 + 1 < m) ? bcnt[xphys(j0 + 1, nbuck)] : 0;
    int c2 = (j0 + 2 < m) ? bcnt[xphys(j0 + 2, nbuck)] : 0;
    int c3 = (j0 + 3 < m) ? bcnt[xphys(j0 + 3, nbuck)] : 0;
    int tsum = c0 + c1 + c2 + c3;
    __shared__ int sh[256];
    sh[threadIdx.x] = tsum;
    __syncthreads();
    for (int d = 1; d < 256; d <<= 1) {
        int t = (threadIdx.x >= d) ? sh[threadIdx.x - d] : 0;
        __syncthreads();
        sh[threadIdx.x] += t;
        __syncthreads();
    }
    int pre = pbase[blockIdx.x] + sh[threadIdx.x] - tsum;
    if (j0 + 0 < m) bofs[xphys(j0 + 0, nbuck)] = pre;
    if (j0 + 1 < m) bofs[xphys(j0 + 1, nbuck)] = pre + c0;
    if (j0 + 2 < m) bofs[xphys(j0 + 2, nbuck)] = pre + c0 + c1;
    if (j0 + 3 < m) bofs[xphys(j0 + 3, nbuck)] = pre + c0 + c1 + c2;
}

// ---------------- pass B: deterministic placement, block-private cursors ---
// pack: v = s | ((d & 255) << 17)   (requires s < 2^17)
__global__ __launch_bounds__(256) void place_pass(const int* __restrict__ src,
                                                  const int* __restrict__ dst,
                                                  const int* __restrict__ bofs,
                                                  int* __restrict__ pairs,
                                                  int n_edges, int nbuck) {
    __shared__ int lcur[MAXBUCK];
    for (int i = threadIdx.x; i < nbuck; i += 256)
        lcur[i] = bofs[blockIdx.x * nbuck + i];
    __syncthreads();
    const int chunk = (n_edges + NBLK - 1) / NBLK;
    const int begin = blockIdx.x * chunk;
    const int end = min(begin + chunk, n_edges);
    for (int e = begin + threadIdx.x; e < end; e += 256) {
        int d = __builtin_nontemporal_load(dst + e);
        int s = __builtin_nontemporal_load(src + e);
        int slot = atomicAdd(&lcur[d >> BSHIFT], 1);
        pairs[slot] = s | ((d & 255) << 17);
    }
}

// ---------------- pass C: per-bucket CSR + off + dis -----------------------
// One block per 256-node bucket; scatter stays in a <=32 KB L2 window.
__global__ __launch_bounds__(256) void csr_bucket(const int* __restrict__ pairs,
                                                  const int* __restrict__ bofs,
                                                  int* __restrict__ off,
                                                  float* __restrict__ dis,
                                                  int* __restrict__ csr,
                                                  int n_nodes, int n_edges, int nbuck) {
    __shared__ int hist[256];
    __shared__ int lofs[256];
    __shared__ int ss[256];
    const int b = blockIdx.x;
    const int node0 = b << BSHIFT;
    const int nn = min(256, n_nodes - node0);
    const int pbeg = bofs[b];                                  // (bucket b, blk 0)
    const int pend = (b + 1 < nbuck) ? bofs[b + 1] : n_edges;
    const int tid = threadIdx.x;
    hist[tid] = 0;
    __syncthreads();
    for (int i = pbeg + tid; i < pend; i += 256)
        atomicAdd(&hist[pairs[i] >> 17], 1);
    __syncthreads();
    int h0 = (tid < nn) ? hist[tid] : 0;
    ss[tid] = h0;
    __syncthreads();
    for (int d = 1; d < 256; d <<= 1) {
        int t = (tid >= d) ? ss[tid - d] : 0;
        __syncthreads();
        ss[tid] += t;
        __syncthreads();
    }
    int pre = pbeg + ss[tid] - h0;   // exclusive, global edge index
    if (tid < nn) {
        lofs[tid] = pre;
        off[node0 + tid] = pre;
        dis[node0 + tid] = rsqrtf((float)(h0 + 1));
    }
    __syncthreads();
    for (int i = pbeg + tid; i < pend; i += 256) {
        int v = pairs[i];
        int slot = atomicAdd(&lofs[v >> 17], 1);
        csr[slot] = v & 0x1FFFF;
    }
    if (b == 0 && tid == 0) off[n_nodes] = n_edges;
}

// ---------------- GEMM 1: xW = x @ W1 ----------------
__global__ __launch_bounds__(256) void gemm_x_w(const float* __restrict__ x,
                                                const float* __restrict__ W,
                                                float* __restrict__ out, int n_nodes) {
    __shared__ float Wl[INC * HIDC];
    __shared__ float xr[4][INC];
    for (int i = threadIdx.x; i < INC * HIDC; i += 256) Wl[i] = W[i];
    const int wid = threadIdx.x >> 6, lane = threadIdx.x & 63;
    for (int base = blockIdx.x * 4; base < n_nodes; base += gridDim.x * 4) {
        int nrows = min(4, n_nodes - base);
        __syncthreads();
        for (int i = threadIdx.x; i < nrows * (INC / 4); i += 256)
            ((float4*)xr)[i] = ((const float4*)(x + (size_t)base * INC))[i];
        __syncthreads();
        if (wid < nrows) {
            float acc = 0.f;
            #pragma unroll
            for (int k = 0; k < INC; ++k) acc += xr[wid][k] * Wl[k * HIDC + lane];
            out[(size_t)(base + wid) * HIDC + lane] = acc;
        }
    }
}

// ---------------- GEMM 2: hw = h @ [W_mu | W_ls] ----------------
__global__ __launch_bounds__(256) void gemm_h_w(const float* __restrict__ h,
                                                const float* __restrict__ Wmu,
                                                const float* __restrict__ Wls,
                                                float* __restrict__ out, int n_nodes) {
    __shared__ float Wl[HIDC * 32];
    __shared__ float hr[8][HIDC];
    for (int i = threadIdx.x; i < HIDC * OUTC; i += 256) {
        int k = i >> 4, c = i & 15;
        Wl[k * 32 + c]      = Wmu[i];
        Wl[k * 32 + 16 + c] = Wls[i];
    }
    const int wid = threadIdx.x >> 6, lane = threadIdx.x & 63;
    const int sub = lane >> 5, ch = lane & 31;
    for (int base = blockIdx.x * 8; base < n_nodes; base += gridDim.x * 8) {
        int nrows = min(8, n_nodes - base);
        __syncthreads();
        for (int i = threadIdx.x; i < nrows * (HIDC / 4); i += 256)
            ((float4*)hr)[i] = ((const float4*)(h + (size_t)base * HIDC))[i];
        __syncthreads();
        int n = wid * 2 + sub;
        if (n < nrows) {
            float acc = 0.f;
            #pragma unroll
            for (int k = 0; k < HIDC; ++k) acc += hr[n][k] * Wl[k * 32 + ch];
            out[(size_t)(base + n) * 32 + ch] = acc;
        }
    }
}

// ---------------- gather conv1: float4, 4 edges in flight per wave ----------
__global__ __launch_bounds__(256) void gather64(const float4* __restrict__ xW4,
                                                float4* __restrict__ h4,
                                                const int* __restrict__ csr,
                                                const int* __restrict__ off,
                                                const float* __restrict__ dis,
                                                const float* __restrict__ b1,
                                                int n_nodes) {
    int node = (blockIdx.x * 256 + threadIdx.x) >> 6;
    int lane = threadIdx.x & 63;
    if (node >= n_nodes) return;
    const int beg = off[node], end = off[node + 1];
    const float dn = dis[node];
    const int sub = lane >> 4;
    const int c4  = lane & 15;
    float4 acc = {0.f, 0.f, 0.f, 0.f};
    for (int base = beg; base < end; base += 64) {
        const int cnt = min(64, end - base);
        int s = 0; float nrm = 0.f;
        if (lane < cnt) {
            s = __builtin_nontemporal_load(csr + base + lane);
            nrm = dis[s] * dn;
        }
        for (int j = 0; j < cnt; j += 4) {
            int jj = j + sub;
            int sj = __shfl(s, jj);
            float nj = __shfl(nrm, jj);
            if (jj < cnt) {
                float4 r = xW4[(size_t)sj * 16 + c4];
                acc.x += r.x * nj; acc.y += r.y * nj;
                acc.z += r.z * nj; acc.w += r.w * nj;
            }
        }
    }
    acc.x += __shfl_xor(acc.x, 16); acc.y += __shfl_xor(acc.y, 16);
    acc.z += __shfl_xor(acc.z, 16); acc.w += __shfl_xor(acc.w, 16);
    acc.x += __shfl_xor(acc.x, 32); acc.y += __shfl_xor(acc.y, 32);
    acc.z += __shfl_xor(acc.z, 32); acc.w += __shfl_xor(acc.w, 32);
    if (sub == 0) {
        float4 self = xW4[(size_t)node * 16 + c4];
        float s2 = dn * dn;
        float4 b = ((const float4*)b1)[c4];
        float4 o;
        o.x = fmaxf(acc.x + self.x * s2 + b.x, 0.f);
        o.y = fmaxf(acc.y + self.y * s2 + b.y, 0.f);
        o.z = fmaxf(acc.z + self.z * s2 + b.z, 0.f);
        o.w = fmaxf(acc.w + self.w * s2 + b.w, 0.f);
        h4[(size_t)node * 16 + c4] = o;
    }
}

// ---------------- gather conv2: float4, 8 edges in flight per wave ----------
__global__ __launch_bounds__(256) void gather32(const float4* __restrict__ hw4,
                                                const int* __restrict__ csr,
                                                const int* __restrict__ off,
                                                const float* __restrict__ dis,
                                                const float* __restrict__ bmu,
                                                const float* __restrict__ bls,
                                                float* __restrict__ out,
                                                int n_nodes) {
    int node = (blockIdx.x * 256 + threadIdx.x) >> 6;
    int lane = threadIdx.x & 63;
    if (node >= n_nodes) return;
    const int beg = off[node], end = off[node + 1];
    const float dn = dis[node];
    const int sub = lane >> 3;
    const int c4  = lane & 7;
    float4 acc = {0.f, 0.f, 0.f, 0.f};
    for (int base = beg; base < end; base += 64) {
        const int cnt = min(64, end - base);
        int s = 0; float nrm = 0.f;
        if (lane < cnt) {
            s = __builtin_nontemporal_load(csr + base + lane);
            nrm = dis[s] * dn;
        }
        for (int j = 0; j < cnt; j += 8) {
            int jj = j + sub;
            int sj = __shfl(s, jj);
            float nj = __shfl(nrm, jj);
            if (jj < cnt) {
                float4 r = hw4[(size_t)sj * 8 + c4];
                acc.x += r.x * nj; acc.y += r.y * nj;
                acc.z += r.z * nj; acc.w += r.w * nj;
            }
        }
    }
    acc.x += __shfl_xor(acc.x, 8);  acc.y += __shfl_xor(acc.y, 8);
    acc.z += __shfl_xor(acc.z, 8);  acc.w += __shfl_xor(acc.w, 8);
    acc.x += __shfl_xor(acc.x, 16); acc.y += __shfl_xor(acc.y, 16);
    acc.z += __shfl_xor(acc.z, 16); acc.w += __shfl_xor(acc.w, 16);
    acc.x += __shfl_xor(acc.x, 32); acc.y += __shfl_xor(acc.y, 32);
    acc.z += __shfl_xor(acc.z, 32); acc.w += __shfl_xor(acc.w, 32);
    if (sub == 0) {
        float4 self = hw4[(size_t)node * 8 + c4];
        float s2 = dn * dn;
        float4 b = (c4 < 4) ? ((const float4*)bmu)[c4] : ((const float4*)bls)[c4 - 4];
        float4 o;
        o.x = acc.x + self.x * s2 + b.x;
        o.y = acc.y + self.y * s2 + b.y;
        o.z = acc.z + self.z * s2 + b.z;
        o.w = acc.w + self.w * s2 + b.w;
        if (c4 < 4)
            ((float4*)out)[(size_t)node * 4 + c4] = o;
        else
            ((float4*)out)[((size_t)n_nodes + node) * 4 + (c4 - 4)] = o;
    }
}

extern "C" void kernel_launch(void* const* d_in, const int* in_sizes, int n_in,
                              void* d_out, int out_size, void* d_ws, size_t ws_size,
                              hipStream_t stream) {
    const float* x   = (const float*)d_in[0];
    const int*   ei  = (const int*)d_in[1];
    const float* W1  = (const float*)d_in[2];
    const float* b1  = (const float*)d_in[3];
    const float* Wmu = (const float*)d_in[4];
    const float* bmu = (const float*)d_in[5];
    const float* Wls = (const float*)d_in[6];
    const float* bls = (const float*)d_in[7];
    float* out = (float*)d_out;

    const int N = in_sizes[0] / INC;       // 100000  (packing needs N < 2^17)
    const int E = in_sizes[1] / 2;         // 3200000
    const int* src = ei;
    const int* dst = ei + E;
    const int NBUCK = (N + 255) >> BSHIFT; // 391
    const int M = NBUCK * NBLK;            // 200192
    const int SBM = (M + 1023) / 1024;     // 196 (<=256 required)

    // workspace (4-byte words):
    //   dis [0,131072) | off [131072,262144)
    //   bcnt [262144, 262144+M) | bofs [462336, 462336+M)
    //   partial/pbase [662528, 663040)
    //   csr [663040, 663040+E) | xW next 64N | h next 64N (pairs aliases h)
    float* ws   = (float*)d_ws;
    float* dis  = ws;
    int*   off  = (int*)(ws + 131072);
    int*   bcnt = (int*)(ws + 262144);
    int*   bofs = (int*)(ws + 462336);
    int*   partial = (int*)(ws + 662528);
    int*   pbase   = partial + 256;
    int*   csr  = (int*)(ws + 663040);
    float* xW   = ws + 663040 + (size_t)E;
    float* h    = xW + (size_t)N * HIDC;
    int*   pairs = (int*)h;                // dead before gather64 writes h
    float* hw   = xW;                      // xW dead after gather64

    count_pass<<<NBLK, 256, 0, stream>>>(dst, bcnt, E, NBUCK);
    mscan_k1<<<SBM, 256, 0, stream>>>(bcnt, partial, M, NBUCK);
    mscan_k2<<<1, 256, 0, stream>>>(partial, pbase, SBM);
    mscan_k3<<<SBM, 256, 0, stream>>>(bcnt, pbase, bofs, M, NBUCK);
    place_pass<<<NBLK, 256, 0, stream>>>(src, dst, bofs, pairs, E, NBUCK);
    csr_bucket<<<NBUCK, 256, 0, stream>>>(pairs, bofs, off, dis, csr, N, E, NBUCK);

    gemm_x_w<<<1024, 256, 0, stream>>>(x, W1, xW, N);
    gather64<<<(N * 64 + 255) / 256, 256, 0, stream>>>((const float4*)xW, (float4*)h,
                                                       csr, off, dis, b1, N);

    gemm_h_w<<<1024, 256, 0, stream>>>(h, Wmu, Wls, hw, N);
    gather32<<<(N * 64 + 255) / 256, 256, 0, stream>>>((const float4*)hw, csr, off, dis,
                                                       bmu, bls, out, N);
}

// Round 7
// 428.704 us; speedup vs baseline: 1.6928x; 1.1185x over previous
//
#include <hip/hip_runtime.h>
#include <hip/hip_bf16.h>

#define HIDC 64
#define INC 128
#define OUTC 16
#define NBLK 512            // blocks in count/place passes (must be pow2)
#define BSHIFT 8            // bucket = 256 nodes
#define MAXBUCK 512         // LDS array bound (nbuck=391 for N=100k)

__device__ __forceinline__ float bflo(unsigned int u) {
    return __uint_as_float(u << 16);
}
__device__ __forceinline__ float bfhi(unsigned int u) {
    return __uint_as_float(u & 0xffff0000u);
}
__device__ __forceinline__ unsigned int f2bf(float f) {  // RNE to bf16 bits
    unsigned int b = __float_as_uint(f);
    return (b + 0x7fffu + ((b >> 16) & 1u)) >> 16;
}

// ---------------- pass A: per-(block,bucket) counts, no global atomics -----
__global__ __launch_bounds__(256) void count_pass(const int* __restrict__ dst,
                                                  int* __restrict__ bcnt,
                                                  int n_edges, int nbuck) {
    __shared__ int lh[MAXBUCK];
    for (int i = threadIdx.x; i < nbuck; i += 256) lh[i] = 0;
    __syncthreads();
    const int chunk = (n_edges + NBLK - 1) / NBLK;
    const int begin = blockIdx.x * chunk;
    const int end = min(begin + chunk, n_edges);
    for (int e = begin + threadIdx.x; e < end; e += 256) {
        int d = __builtin_nontemporal_load(dst + e);
        atomicAdd(&lh[d >> BSHIFT], 1);
    }
    __syncthreads();
    for (int i = threadIdx.x; i < nbuck; i += 256)
        bcnt[blockIdx.x * nbuck + i] = lh[i];
}

// ---------------- scan of the count matrix in bucket-major logical order ---
// logical j = bucket*NBLK + blk  ->  physical p = blk*nbuck + bucket
__device__ __forceinline__ int xphys(int j, int nbuck) {
    return (j & (NBLK - 1)) * nbuck + (j >> 9);
}

__global__ __launch_bounds__(256) void mscan_k1(const int* __restrict__ bcnt,
                                                int* __restrict__ partial,
                                                int m, int nbuck) {
    int base = blockIdx.x * 1024;
    int lim = min(base + 1024, m);
    int s = 0;
    for (int j = base + threadIdx.x; j < lim; j += 256) s += bcnt[xphys(j, nbuck)];
    #pragma unroll
    for (int d = 32; d; d >>= 1) s += __shfl_down(s, d);
    __shared__ int wsum[4];
    if ((threadIdx.x & 63) == 0) wsum[threadIdx.x >> 6] = s;
    __syncthreads();
    if (threadIdx.x == 0) partial[blockIdx.x] = wsum[0] + wsum[1] + wsum[2] + wsum[3];
}

__global__ __launch_bounds__(256) void mscan_k2(const int* __restrict__ partial,
                                                int* __restrict__ pbase, int nblk) {
    __shared__ int sh[256];
    int v = (threadIdx.x < nblk) ? partial[threadIdx.x] : 0;
    sh[threadIdx.x] = v;
    __syncthreads();
    for (int d = 1; d < 256; d <<= 1) {
        int t = (threadIdx.x >= d) ? sh[threadIdx.x - d] : 0;
        __syncthreads();
        sh[threadIdx.x] += t;
        __syncthreads();
    }
    if (threadIdx.x < nblk) pbase[threadIdx.x] = sh[threadIdx.x] - v;
}

__global__ __launch_bounds__(256) void mscan_k3(const int* __restrict__ bcnt,
                                                const int* __restrict__ pbase,
                                                int* __restrict__ bofs,
                                                int m, int nbuck) {
    int j0 = blockIdx.x * 1024 + threadIdx.x * 4;
    int c0 = (j0 + 0 < m) ? bcnt[xphys(j0 + 0, nbuck)] : 0;
    int c1 = (j0 + 1 < m) ? bcnt[xphys(j0 + 1, nbuck)] : 0;
    int c2 = (j0 + 2 < m) ? bcnt[xphys(j0 + 2, nbuck)] : 0;
    int c3 = (j0 + 3 < m) ? bcnt[xphys(j0 + 3, nbuck)] : 0;
    int tsum = c0 + c1 + c2 + c3;
    __shared__ int sh[256];
    sh[threadIdx.x] = tsum;
    __syncthreads();
    for (int d = 1; d < 256; d <<= 1) {
        int t = (threadIdx.x >= d) ? sh[threadIdx.x - d] : 0;
        __syncthreads();
        sh[threadIdx.x] += t;
        __syncthreads();
    }
    int pre = pbase[blockIdx.x] + sh[threadIdx.x] - tsum;
    if (j0 + 0 < m) bofs[xphys(j0 + 0, nbuck)] = pre;
    if (j0 + 1 < m) bofs[xphys(j0 + 1, nbuck)] = pre + c0;
    if (j0 + 2 < m) bofs[xphys(j0 + 2, nbuck)] = pre + c0 + c1;
    if (j0 + 3 < m) bofs[xphys(j0 + 3, nbuck)] = pre + c0 + c1 + c2;
}

// ---------------- pass B: deterministic placement, block-private cursors ---
__global__ __launch_bounds__(256) void place_pass(const int* __restrict__ src,
                                                  const int* __restrict__ dst,
                                                  const int* __restrict__ bofs,
                                                  int* __restrict__ pairs,
                                                  int n_edges, int nbuck) {
    __shared__ int lcur[MAXBUCK];
    for (int i = threadIdx.x; i < nbuck; i += 256)
        lcur[i] = bofs[blockIdx.x * nbuck + i];
    __syncthreads();
    const int chunk = (n_edges + NBLK - 1) / NBLK;
    const int begin = blockIdx.x * chunk;
    const int end = min(begin + chunk, n_edges);
    for (int e = begin + threadIdx.x; e < end; e += 256) {
        int d = __builtin_nontemporal_load(dst + e);
        int s = __builtin_nontemporal_load(src + e);
        int slot = atomicAdd(&lcur[d >> BSHIFT], 1);
        pairs[slot] = s | ((d & 255) << 17);
    }
}

// ---------------- pass C: per-bucket CSR + off + dis -----------------------
__global__ __launch_bounds__(256) void csr_bucket(const int* __restrict__ pairs,
                                                  const int* __restrict__ bofs,
                                                  int* __restrict__ off,
                                                  float* __restrict__ dis,
                                                  int* __restrict__ csr,
                                                  int n_nodes, int n_edges, int nbuck) {
    __shared__ int hist[256];
    __shared__ int lofs[256];
    __shared__ int ss[256];
    const int b = blockIdx.x;
    const int node0 = b << BSHIFT;
    const int nn = min(256, n_nodes - node0);
    const int pbeg = bofs[b];
    const int pend = (b + 1 < nbuck) ? bofs[b + 1] : n_edges;
    const int tid = threadIdx.x;
    hist[tid] = 0;
    __syncthreads();
    for (int i = pbeg + tid; i < pend; i += 256)
        atomicAdd(&hist[pairs[i] >> 17], 1);
    __syncthreads();
    int h0 = (tid < nn) ? hist[tid] : 0;
    ss[tid] = h0;
    __syncthreads();
    for (int d = 1; d < 256; d <<= 1) {
        int t = (tid >= d) ? ss[tid - d] : 0;
        __syncthreads();
        ss[tid] += t;
        __syncthreads();
    }
    int pre = pbeg + ss[tid] - h0;
    if (tid < nn) {
        lofs[tid] = pre;
        off[node0 + tid] = pre;
        dis[node0 + tid] = rsqrtf((float)(h0 + 1));
    }
    __syncthreads();
    for (int i = pbeg + tid; i < pend; i += 256) {
        int v = pairs[i];
        int slot = atomicAdd(&lofs[v >> 17], 1);
        csr[slot] = v & 0x1FFFF;
    }
    if (b == 0 && tid == 0) off[n_nodes] = n_edges;
}

// ---------------- GEMM 1: xWb = bf16(x @ W1) ----------------
__global__ __launch_bounds__(256) void gemm_x_w(const float* __restrict__ x,
                                                const float* __restrict__ W,
                                                unsigned int* __restrict__ xWb,
                                                int n_nodes) {
    __shared__ float Wl[INC * HIDC];
    __shared__ float xr[4][INC];
    for (int i = threadIdx.x; i < INC * HIDC; i += 256) Wl[i] = W[i];
    const int wid = threadIdx.x >> 6, lane = threadIdx.x & 63;
    for (int base = blockIdx.x * 4; base < n_nodes; base += gridDim.x * 4) {
        int nrows = min(4, n_nodes - base);
        __syncthreads();
        for (int i = threadIdx.x; i < nrows * (INC / 4); i += 256)
            ((float4*)xr)[i] = ((const float4*)(x + (size_t)base * INC))[i];
        __syncthreads();
        if (wid < nrows) {
            float acc = 0.f;
            #pragma unroll
            for (int k = 0; k < INC; ++k) acc += xr[wid][k] * Wl[k * HIDC + lane];
            unsigned int bf = f2bf(acc);
            unsigned int hi = (unsigned int)__shfl_down((int)bf, 1);
            if (!(lane & 1))
                xWb[((size_t)(base + wid) * HIDC + lane) >> 1] = bf | (hi << 16);
        }
    }
}

// ---------------- GEMM 2: hwb = bf16(h @ [W_mu | W_ls]) ----------------
__global__ __launch_bounds__(256) void gemm_h_w(const float* __restrict__ h,
                                                const float* __restrict__ Wmu,
                                                const float* __restrict__ Wls,
                                                unsigned int* __restrict__ hwb,
                                                int n_nodes) {
    __shared__ float Wl[HIDC * 32];
    __shared__ float hr[8][HIDC];
    for (int i = threadIdx.x; i < HIDC * OUTC; i += 256) {
        int k = i >> 4, c = i & 15;
        Wl[k * 32 + c]      = Wmu[i];
        Wl[k * 32 + 16 + c] = Wls[i];
    }
    const int wid = threadIdx.x >> 6, lane = threadIdx.x & 63;
    const int sub = lane >> 5, ch = lane & 31;
    for (int base = blockIdx.x * 8; base < n_nodes; base += gridDim.x * 8) {
        int nrows = min(8, n_nodes - base);
        __syncthreads();
        for (int i = threadIdx.x; i < nrows * (HIDC / 4); i += 256)
            ((float4*)hr)[i] = ((const float4*)(h + (size_t)base * HIDC))[i];
        __syncthreads();
        int n = wid * 2 + sub;
        if (n < nrows) {
            float acc = 0.f;
            #pragma unroll
            for (int k = 0; k < HIDC; ++k) acc += hr[n][k] * Wl[k * 32 + ch];
            unsigned int bf = f2bf(acc);
            unsigned int hi = (unsigned int)__shfl_down((int)bf, 1);
            if (!(ch & 1))
                hwb[((size_t)(base + n) * 32 + ch) >> 1] = bf | (hi << 16);
        }
    }
}

// ---------------- gather conv1: bf16 rows (128 B), 8 edges in flight -------
// 8 lanes cover a row (uint4 = 8 channels each); sub = lane>>3 picks edge.
__global__ __launch_bounds__(256) void gather64(const uint4* __restrict__ xWb4,
                                                float4* __restrict__ h4,
                                                const int* __restrict__ csr,
                                                const int* __restrict__ off,
                                                const float* __restrict__ dis,
                                                const float* __restrict__ b1,
                                                int n_nodes) {
    int node = (blockIdx.x * 256 + threadIdx.x) >> 6;
    int lane = threadIdx.x & 63;
    if (node >= n_nodes) return;
    const int beg = off[node], end = off[node + 1];
    const float dn = dis[node];
    const int sub = lane >> 3;
    const int c8  = lane & 7;
    float a0 = 0.f, a1 = 0.f, a2 = 0.f, a3 = 0.f, a4 = 0.f, a5 = 0.f, a6 = 0.f, a7 = 0.f;
    for (int base = beg; base < end; base += 64) {
        const int cnt = min(64, end - base);
        int s = 0; float nrm = 0.f;
        if (lane < cnt) {
            s = __builtin_nontemporal_load(csr + base + lane);
            nrm = dis[s] * dn;
        }
        for (int j = 0; j < cnt; j += 8) {
            int jj = j + sub;
            int sj = __shfl(s, jj);
            float nj = __shfl(nrm, jj);
            if (jj < cnt) {
                uint4 r = xWb4[(size_t)sj * 8 + c8];
                a0 += bflo(r.x) * nj; a1 += bfhi(r.x) * nj;
                a2 += bflo(r.y) * nj; a3 += bfhi(r.y) * nj;
                a4 += bflo(r.z) * nj; a5 += bfhi(r.z) * nj;
                a6 += bflo(r.w) * nj; a7 += bfhi(r.w) * nj;
            }
        }
    }
    #pragma unroll
    for (int m = 8; m <= 32; m <<= 1) {
        a0 += __shfl_xor(a0, m); a1 += __shfl_xor(a1, m);
        a2 += __shfl_xor(a2, m); a3 += __shfl_xor(a3, m);
        a4 += __shfl_xor(a4, m); a5 += __shfl_xor(a5, m);
        a6 += __shfl_xor(a6, m); a7 += __shfl_xor(a7, m);
    }
    if (sub == 0) {
        uint4 r = xWb4[(size_t)node * 8 + c8];
        float s2 = dn * dn;
        a0 += bflo(r.x) * s2; a1 += bfhi(r.x) * s2;
        a2 += bflo(r.y) * s2; a3 += bfhi(r.y) * s2;
        a4 += bflo(r.z) * s2; a5 += bfhi(r.z) * s2;
        a6 += bflo(r.w) * s2; a7 += bfhi(r.w) * s2;
        float4 bA = ((const float4*)b1)[c8 * 2];
        float4 bB = ((const float4*)b1)[c8 * 2 + 1];
        float4 o1, o2;
        o1.x = fmaxf(a0 + bA.x, 0.f); o1.y = fmaxf(a1 + bA.y, 0.f);
        o1.z = fmaxf(a2 + bA.z, 0.f); o1.w = fmaxf(a3 + bA.w, 0.f);
        o2.x = fmaxf(a4 + bB.x, 0.f); o2.y = fmaxf(a5 + bB.y, 0.f);
        o2.z = fmaxf(a6 + bB.z, 0.f); o2.w = fmaxf(a7 + bB.w, 0.f);
        h4[(size_t)node * 16 + c8 * 2]     = o1;
        h4[(size_t)node * 16 + c8 * 2 + 1] = o2;
    }
}

// ---------------- gather conv2: bf16 rows (64 B), 16 edges in flight -------
// 4 lanes cover a row; sub = lane>>2 picks edge.
__global__ __launch_bounds__(256) void gather32(const uint4* __restrict__ hwb4,
                                                const int* __restrict__ csr,
                                                const int* __restrict__ off,
                                                const float* __restrict__ dis,
                                                const float* __restrict__ bmu,
                                                const float* __restrict__ bls,
                                                float* __restrict__ out,
                                                int n_nodes) {
    int node = (blockIdx.x * 256 + threadIdx.x) >> 6;
    int lane = threadIdx.x & 63;
    if (node >= n_nodes) return;
    const int beg = off[node], end = off[node + 1];
    const float dn = dis[node];
    const int sub = lane >> 2;
    const int c4  = lane & 3;
    float a0 = 0.f, a1 = 0.f, a2 = 0.f, a3 = 0.f, a4 = 0.f, a5 = 0.f, a6 = 0.f, a7 = 0.f;
    for (int base = beg; base < end; base += 64) {
        const int cnt = min(64, end - base);
        int s = 0; float nrm = 0.f;
        if (lane < cnt) {
            s = __builtin_nontemporal_load(csr + base + lane);
            nrm = dis[s] * dn;
        }
        for (int j = 0; j < cnt; j += 16) {
            int jj = j + sub;
            int sj = __shfl(s, jj);
            float nj = __shfl(nrm, jj);
            if (jj < cnt) {
                uint4 r = hwb4[(size_t)sj * 4 + c4];
                a0 += bflo(r.x) * nj; a1 += bfhi(r.x) * nj;
                a2 += bflo(r.y) * nj; a3 += bfhi(r.y) * nj;
                a4 += bflo(r.z) * nj; a5 += bfhi(r.z) * nj;
                a6 += bflo(r.w) * nj; a7 += bfhi(r.w) * nj;
            }
        }
    }
    #pragma unroll
    for (int m = 4; m <= 32; m <<= 1) {
        a0 += __shfl_xor(a0, m); a1 += __shfl_xor(a1, m);
        a2 += __shfl_xor(a2, m); a3 += __shfl_xor(a3, m);
        a4 += __shfl_xor(a4, m); a5 += __shfl_xor(a5, m);
        a6 += __shfl_xor(a6, m); a7 += __shfl_xor(a7, m);
    }
    if (sub == 0) {
        uint4 r = hwb4[(size_t)node * 4 + c4];
        float s2 = dn * dn;
        a0 += bflo(r.x) * s2; a1 += bfhi(r.x) * s2;
        a2 += bflo(r.y) * s2; a3 += bfhi(r.y) * s2;
        a4 += bflo(r.z) * s2; a5 += bfhi(r.z) * s2;
        a6 += bflo(r.w) * s2; a7 += bfhi(r.w) * s2;
        const float4* bsrc = (c4 < 2) ? (const float4*)bmu : (const float4*)bls;
        int bi = (c4 & 1) * 2;
        float4 bA = bsrc[bi], bB = bsrc[bi + 1];
        float4 o1, o2;
        o1.x = a0 + bA.x; o1.y = a1 + bA.y; o1.z = a2 + bA.z; o1.w = a3 + bA.w;
        o2.x = a4 + bB.x; o2.y = a5 + bB.y; o2.z = a6 + bB.z; o2.w = a7 + bB.w;
        size_t rowbase = (c4 < 2) ? (size_t)node * 4 : ((size_t)n_nodes + node) * 4;
        ((float4*)out)[rowbase + (c4 & 1) * 2]     = o1;
        ((float4*)out)[rowbase + (c4 & 1) * 2 + 1] = o2;
    }
}

extern "C" void kernel_launch(void* const* d_in, const int* in_sizes, int n_in,
                              void* d_out, int out_size, void* d_ws, size_t ws_size,
                              hipStream_t stream) {
    const float* x   = (const float*)d_in[0];
    const int*   ei  = (const int*)d_in[1];
    const float* W1  = (const float*)d_in[2];
    const float* b1  = (const float*)d_in[3];
    const float* Wmu = (const float*)d_in[4];
    const float* bmu = (const float*)d_in[5];
    const float* Wls = (const float*)d_in[6];
    const float* bls = (const float*)d_in[7];
    float* out = (float*)d_out;

    const int N = in_sizes[0] / INC;       // 100000  (packing needs N < 2^17)
    const int E = in_sizes[1] / 2;         // 3200000
    const int* src = ei;
    const int* dst = ei + E;
    const int NBUCK = (N + 255) >> BSHIFT; // 391
    const int M = NBUCK * NBLK;            // 200192
    const int SBM = (M + 1023) / 1024;     // 196 (<=256 required)

    // workspace (4-byte words):
    //   dis [0,131072) | off [131072,262144)
    //   bcnt [262144, 262144+M) | bofs [462336, 462336+M)
    //   partial/pbase [662528, 663040)
    //   csr [663040, 663040+E)
    //   xWb (bf16, N*32 words) next | h (fp32, N*64 words) next
    //   hwb aliases xWb; pairs aliases h
    float* ws   = (float*)d_ws;
    float* dis  = ws;
    int*   off  = (int*)(ws + 131072);
    int*   bcnt = (int*)(ws + 262144);
    int*   bofs = (int*)(ws + 462336);
    int*   partial = (int*)(ws + 662528);
    int*   pbase   = partial + 256;
    int*   csr  = (int*)(ws + 663040);
    unsigned int* xWb = (unsigned int*)(ws + 663040 + (size_t)E);
    float* h    = (float*)(xWb + (size_t)N * 32);
    int*   pairs = (int*)h;                      // dead before gather64 writes h
    unsigned int* hwb = xWb;                     // xWb dead after gather64

    count_pass<<<NBLK, 256, 0, stream>>>(dst, bcnt, E, NBUCK);
    mscan_k1<<<SBM, 256, 0, stream>>>(bcnt, partial, M, NBUCK);
    mscan_k2<<<1, 256, 0, stream>>>(partial, pbase, SBM);
    mscan_k3<<<SBM, 256, 0, stream>>>(bcnt, pbase, bofs, M, NBUCK);
    place_pass<<<NBLK, 256, 0, stream>>>(src, dst, bofs, pairs, E, NBUCK);
    csr_bucket<<<NBUCK, 256, 0, stream>>>(pairs, bofs, off, dis, csr, N, E, NBUCK);

    gemm_x_w<<<1024, 256, 0, stream>>>(x, W1, xWb, N);
    gather64<<<(N * 64 + 255) / 256, 256, 0, stream>>>((const uint4*)xWb, (float4*)h,
                                                       csr, off, dis, b1, N);

    gemm_h_w<<<1024, 256, 0, stream>>>(h, Wmu, Wls, hwb, N);
    gather32<<<(N * 64 + 255) / 256, 256, 0, stream>>>((const uint4*)hwb, csr, off, dis,
                                                       bmu, bls, out, N);
}

// Round 8
// 351.518 us; speedup vs baseline: 2.0644x; 1.2196x over previous
//
#include <hip/hip_runtime.h>
#include <hip/hip_bf16.h>

#define HIDC 64
#define INC 128
#define OUTC 16
#define NBLK 512            // blocks in count/place passes (must be pow2)
#define BSHIFT 8            // bucket = 256 nodes
#define MAXBUCK 512         // LDS array bound (nbuck=391 for N=100k)

typedef __attribute__((ext_vector_type(8))) short bf16x8;
typedef __attribute__((ext_vector_type(4))) float f32x4;

__device__ __forceinline__ float bflo(unsigned int u) {
    return __uint_as_float(u << 16);
}
__device__ __forceinline__ float bfhi(unsigned int u) {
    return __uint_as_float(u & 0xffff0000u);
}
__device__ __forceinline__ unsigned int f2bf(float f) {  // RNE to bf16 bits
    unsigned int b = __float_as_uint(f);
    return (b + 0x7fffu + ((b >> 16) & 1u)) >> 16;
}

// ---------------- pass A: per-(block,bucket) counts, no global atomics -----
__global__ __launch_bounds__(256) void count_pass(const int* __restrict__ dst,
                                                  int* __restrict__ bcnt,
                                                  int n_edges, int nbuck) {
    __shared__ int lh[MAXBUCK];
    for (int i = threadIdx.x; i < nbuck; i += 256) lh[i] = 0;
    __syncthreads();
    const int chunk = (n_edges + NBLK - 1) / NBLK;
    const int begin = blockIdx.x * chunk;
    const int end = min(begin + chunk, n_edges);
    for (int e = begin + threadIdx.x; e < end; e += 256) {
        int d = __builtin_nontemporal_load(dst + e);
        atomicAdd(&lh[d >> BSHIFT], 1);
    }
    __syncthreads();
    for (int i = threadIdx.x; i < nbuck; i += 256)
        bcnt[blockIdx.x * nbuck + i] = lh[i];
}

// logical j = bucket*NBLK + blk  ->  physical p = blk*nbuck + bucket
__device__ __forceinline__ int xphys(int j, int nbuck) {
    return (j & (NBLK - 1)) * nbuck + (j >> 9);
}

__global__ __launch_bounds__(256) void mscan_k1(const int* __restrict__ bcnt,
                                                int* __restrict__ partial,
                                                int m, int nbuck) {
    int base = blockIdx.x * 1024;
    int lim = min(base + 1024, m);
    int s = 0;
    for (int j = base + threadIdx.x; j < lim; j += 256) s += bcnt[xphys(j, nbuck)];
    #pragma unroll
    for (int d = 32; d; d >>= 1) s += __shfl_down(s, d);
    __shared__ int wsum[4];
    if ((threadIdx.x & 63) == 0) wsum[threadIdx.x >> 6] = s;
    __syncthreads();
    if (threadIdx.x == 0) partial[blockIdx.x] = wsum[0] + wsum[1] + wsum[2] + wsum[3];
}

__global__ __launch_bounds__(256) void mscan_k2(const int* __restrict__ partial,
                                                int* __restrict__ pbase, int nblk) {
    __shared__ int sh[256];
    int v = (threadIdx.x < nblk) ? partial[threadIdx.x] : 0;
    sh[threadIdx.x] = v;
    __syncthreads();
    for (int d = 1; d < 256; d <<= 1) {
        int t = (threadIdx.x >= d) ? sh[threadIdx.x - d] : 0;
        __syncthreads();
        sh[threadIdx.x] += t;
        __syncthreads();
    }
    if (threadIdx.x < nblk) pbase[threadIdx.x] = sh[threadIdx.x] - v;
}

__global__ __launch_bounds__(256) void mscan_k3(const int* __restrict__ bcnt,
                                                const int* __restrict__ pbase,
                                                int* __restrict__ bofs,
                                                int m, int nbuck) {
    int j0 = blockIdx.x * 1024 + threadIdx.x * 4;
    int c0 = (j0 + 0 < m) ? bcnt[xphys(j0 + 0, nbuck)] : 0;
    int c1 = (j0 + 1 < m) ? bcnt[xphys(j0 + 1, nbuck)] : 0;
    int c2 = (j0 + 2 < m) ? bcnt[xphys(j0 + 2, nbuck)] : 0;
    int c3 = (j0 + 3 < m) ? bcnt[xphys(j0 + 3, nbuck)] : 0;
    int tsum = c0 + c1 + c2 + c3;
    __shared__ int sh[256];
    sh[threadIdx.x] = tsum;
    __syncthreads();
    for (int d = 1; d < 256; d <<= 1) {
        int t = (threadIdx.x >= d) ? sh[threadIdx.x - d] : 0;
        __syncthreads();
        sh[threadIdx.x] += t;
        __syncthreads();
    }
    int pre = pbase[blockIdx.x] + sh[threadIdx.x] - tsum;
    if (j0 + 0 < m) bofs[xphys(j0 + 0, nbuck)] = pre;
    if (j0 + 1 < m) bofs[xphys(j0 + 1, nbuck)] = pre + c0;
    if (j0 + 2 < m) bofs[xphys(j0 + 2, nbuck)] = pre + c0 + c1;
    if (j0 + 3 < m) bofs[xphys(j0 + 3, nbuck)] = pre + c0 + c1 + c2;
}

// ---------------- pass B: deterministic placement, block-private cursors ---
__global__ __launch_bounds__(256) void place_pass(const int* __restrict__ src,
                                                  const int* __restrict__ dst,
                                                  const int* __restrict__ bofs,
                                                  int* __restrict__ pairs,
                                                  int n_edges, int nbuck) {
    __shared__ int lcur[MAXBUCK];
    for (int i = threadIdx.x; i < nbuck; i += 256)
        lcur[i] = bofs[blockIdx.x * nbuck + i];
    __syncthreads();
    const int chunk = (n_edges + NBLK - 1) / NBLK;
    const int begin = blockIdx.x * chunk;
    const int end = min(begin + chunk, n_edges);
    for (int e = begin + threadIdx.x; e < end; e += 256) {
        int d = __builtin_nontemporal_load(dst + e);
        int s = __builtin_nontemporal_load(src + e);
        int slot = atomicAdd(&lcur[d >> BSHIFT], 1);
        pairs[slot] = s | ((d & 255) << 17);
    }
}

// ---------------- pass C: per-bucket CSR + off + dis -----------------------
__global__ __launch_bounds__(256) void csr_bucket(const int* __restrict__ pairs,
                                                  const int* __restrict__ bofs,
                                                  int* __restrict__ off,
                                                  float* __restrict__ dis,
                                                  int* __restrict__ csr,
                                                  int n_nodes, int n_edges, int nbuck) {
    __shared__ int hist[256];
    __shared__ int lofs[256];
    __shared__ int ss[256];
    const int b = blockIdx.x;
    const int node0 = b << BSHIFT;
    const int nn = min(256, n_nodes - node0);
    const int pbeg = bofs[b];
    const int pend = (b + 1 < nbuck) ? bofs[b + 1] : n_edges;
    const int tid = threadIdx.x;
    hist[tid] = 0;
    __syncthreads();
    for (int i = pbeg + tid; i < pend; i += 256)
        atomicAdd(&hist[pairs[i] >> 17], 1);
    __syncthreads();
    int h0 = (tid < nn) ? hist[tid] : 0;
    ss[tid] = h0;
    __syncthreads();
    for (int d = 1; d < 256; d <<= 1) {
        int t = (tid >= d) ? ss[tid - d] : 0;
        __syncthreads();
        ss[tid] += t;
        __syncthreads();
    }
    int pre = pbeg + ss[tid] - h0;
    if (tid < nn) {
        lofs[tid] = pre;
        off[node0 + tid] = pre;
        dis[node0 + tid] = rsqrtf((float)(h0 + 1));
    }
    __syncthreads();
    for (int i = pbeg + tid; i < pend; i += 256) {
        int v = pairs[i];
        int slot = atomicAdd(&lofs[v >> 17], 1);
        csr[slot] = v & 0x1FFFF;
    }
    if (b == 0 && tid == 0) off[n_nodes] = n_edges;
}

// ---------------- GEMM 1 (MFMA): xWb = bf16( bf16(x) @ bf16(W1) ) ----------
// Block = 64 rows (4 waves x 16). B-frags (16) live in registers all kernel.
// Layouts (HW-verified): A[m=lane&15][k=quad*8+j]; D col=lane&15,row=quad*4+r.
__global__ __launch_bounds__(256) void gemm1_mfma(const float* __restrict__ x,
                                                  const float* __restrict__ W,
                                                  unsigned int* __restrict__ xWb,
                                                  int n_nodes) {
    __shared__ unsigned short WbT[64][136];   // [n][k], pad 8 -> 2-way banks (free)
    __shared__ unsigned short xs[64][136];    // [m][k]
    const int tid = threadIdx.x;
    const int lane = tid & 63, wave = tid >> 6;
    const int quad = lane >> 4, l16 = lane & 15;
    for (int i = tid; i < INC * HIDC; i += 256) {
        int k = i >> 6, n = i & 63;
        WbT[n][k] = (unsigned short)f2bf(W[i]);
    }
    __syncthreads();
    bf16x8 bfr[4][4];
    #pragma unroll
    for (int nt = 0; nt < 4; ++nt)
        #pragma unroll
        for (int kt = 0; kt < 4; ++kt)
            bfr[nt][kt] = *(const bf16x8*)&WbT[nt * 16 + l16][kt * 32 + quad * 8];

    for (int base = blockIdx.x * 64; base < n_nodes; base += gridDim.x * 64) {
        int nrows = min(64, n_nodes - base);
        __syncthreads();
        for (int i = tid; i < nrows * 32; i += 256) {
            int m = i >> 5, kq = i & 31;
            float4 v = ((const float4*)(x + (size_t)(base + m) * INC))[kq];
            unsigned int* xp = (unsigned int*)&xs[m][kq * 4];
            xp[0] = f2bf(v.x) | (f2bf(v.y) << 16);
            xp[1] = f2bf(v.z) | (f2bf(v.w) << 16);
        }
        __syncthreads();
        int mrow = wave * 16;
        if (mrow < nrows) {
            bf16x8 af[4];
            #pragma unroll
            for (int kt = 0; kt < 4; ++kt)
                af[kt] = *(const bf16x8*)&xs[mrow + l16][kt * 32 + quad * 8];
            f32x4 acc[4];
            #pragma unroll
            for (int nt = 0; nt < 4; ++nt) acc[nt] = (f32x4){0.f, 0.f, 0.f, 0.f};
            #pragma unroll
            for (int kt = 0; kt < 4; ++kt)
                #pragma unroll
                for (int nt = 0; nt < 4; ++nt)
                    acc[nt] = __builtin_amdgcn_mfma_f32_16x16x32_bf16(
                        af[kt], bfr[nt][kt], acc[nt], 0, 0, 0);
            #pragma unroll
            for (int nt = 0; nt < 4; ++nt) {
                #pragma unroll
                for (int r = 0; r < 4; ++r) {
                    unsigned int bv = f2bf(acc[nt][r]);
                    unsigned int hv = (unsigned int)__shfl_down((int)bv, 1);
                    int row = base + mrow + quad * 4 + r;
                    if (!(l16 & 1) && row < n_nodes)
                        xWb[((size_t)row * 64 + nt * 16 + l16) >> 1] = bv | (hv << 16);
                }
            }
        }
    }
}

// ---------------- GEMM 2 (MFMA): hwb = bf16( hb @ [W_mu|W_ls] ) ------------
__global__ __launch_bounds__(256) void gemm2_mfma(const uint4* __restrict__ hb4,
                                                  const float* __restrict__ Wmu,
                                                  const float* __restrict__ Wls,
                                                  unsigned int* __restrict__ hwb,
                                                  int n_nodes) {
    __shared__ unsigned short WT2[32][72];    // [n][k]
    __shared__ unsigned short hs[64][72];     // [m][k]
    const int tid = threadIdx.x;
    const int lane = tid & 63, wave = tid >> 6;
    const int quad = lane >> 4, l16 = lane & 15;
    for (int i = tid; i < HIDC * 32; i += 256) {
        int n = i & 31, k = i >> 5;
        float v = (n < 16) ? Wmu[k * 16 + n] : Wls[k * 16 + (n - 16)];
        WT2[n][k] = (unsigned short)f2bf(v);
    }
    __syncthreads();
    bf16x8 bfr[2][2];
    #pragma unroll
    for (int nt = 0; nt < 2; ++nt)
        #pragma unroll
        for (int kt = 0; kt < 2; ++kt)
            bfr[nt][kt] = *(const bf16x8*)&WT2[nt * 16 + l16][kt * 32 + quad * 8];

    for (int base = blockIdx.x * 64; base < n_nodes; base += gridDim.x * 64) {
        int nrows = min(64, n_nodes - base);
        __syncthreads();
        for (int i = tid; i < nrows * 8; i += 256) {
            int m = i >> 3, q = i & 7;
            uint4 v = hb4[(size_t)(base + m) * 8 + q];
            unsigned int* hp = (unsigned int*)&hs[m][q * 8];
            hp[0] = v.x; hp[1] = v.y; hp[2] = v.z; hp[3] = v.w;
        }
        __syncthreads();
        int mrow = wave * 16;
        if (mrow < nrows) {
            bf16x8 af[2];
            #pragma unroll
            for (int kt = 0; kt < 2; ++kt)
                af[kt] = *(const bf16x8*)&hs[mrow + l16][kt * 32 + quad * 8];
            f32x4 acc[2];
            #pragma unroll
            for (int nt = 0; nt < 2; ++nt) acc[nt] = (f32x4){0.f, 0.f, 0.f, 0.f};
            #pragma unroll
            for (int kt = 0; kt < 2; ++kt)
                #pragma unroll
                for (int nt = 0; nt < 2; ++nt)
                    acc[nt] = __builtin_amdgcn_mfma_f32_16x16x32_bf16(
                        af[kt], bfr[nt][kt], acc[nt], 0, 0, 0);
            #pragma unroll
            for (int nt = 0; nt < 2; ++nt) {
                #pragma unroll
                for (int r = 0; r < 4; ++r) {
                    unsigned int bv = f2bf(acc[nt][r]);
                    unsigned int hv = (unsigned int)__shfl_down((int)bv, 1);
                    int row = base + mrow + quad * 4 + r;
                    if (!(l16 & 1) && row < n_nodes)
                        hwb[((size_t)row * 32 + nt * 16 + l16) >> 1] = bv | (hv << 16);
                }
            }
        }
    }
}

// ---------------- gather conv1: bf16 rows in, bf16 h out -------------------
__global__ __launch_bounds__(256) void gather64(const uint4* __restrict__ xWb4,
                                                uint4* __restrict__ hb4,
                                                const int* __restrict__ csr,
                                                const int* __restrict__ off,
                                                const float* __restrict__ dis,
                                                const float* __restrict__ b1,
                                                int n_nodes) {
    int node = (blockIdx.x * 256 + threadIdx.x) >> 6;
    int lane = threadIdx.x & 63;
    if (node >= n_nodes) return;
    const int beg = off[node], end = off[node + 1];
    const float dn = dis[node];
    const int sub = lane >> 3;
    const int c8  = lane & 7;
    float a0 = 0.f, a1 = 0.f, a2 = 0.f, a3 = 0.f, a4 = 0.f, a5 = 0.f, a6 = 0.f, a7 = 0.f;
    for (int base = beg; base < end; base += 64) {
        const int cnt = min(64, end - base);
        int s = 0; float nrm = 0.f;
        if (lane < cnt) {
            s = __builtin_nontemporal_load(csr + base + lane);
            nrm = dis[s] * dn;
        }
        for (int j = 0; j < cnt; j += 8) {
            int jj = j + sub;
            int sj = __shfl(s, jj);
            float nj = __shfl(nrm, jj);
            if (jj < cnt) {
                uint4 r = xWb4[(size_t)sj * 8 + c8];
                a0 += bflo(r.x) * nj; a1 += bfhi(r.x) * nj;
                a2 += bflo(r.y) * nj; a3 += bfhi(r.y) * nj;
                a4 += bflo(r.z) * nj; a5 += bfhi(r.z) * nj;
                a6 += bflo(r.w) * nj; a7 += bfhi(r.w) * nj;
            }
        }
    }
    #pragma unroll
    for (int m = 8; m <= 32; m <<= 1) {
        a0 += __shfl_xor(a0, m); a1 += __shfl_xor(a1, m);
        a2 += __shfl_xor(a2, m); a3 += __shfl_xor(a3, m);
        a4 += __shfl_xor(a4, m); a5 += __shfl_xor(a5, m);
        a6 += __shfl_xor(a6, m); a7 += __shfl_xor(a7, m);
    }
    if (sub == 0) {
        uint4 r = xWb4[(size_t)node * 8 + c8];
        float s2 = dn * dn;
        a0 += bflo(r.x) * s2; a1 += bfhi(r.x) * s2;
        a2 += bflo(r.y) * s2; a3 += bfhi(r.y) * s2;
        a4 += bflo(r.z) * s2; a5 += bfhi(r.z) * s2;
        a6 += bflo(r.w) * s2; a7 += bfhi(r.w) * s2;
        float4 bA = ((const float4*)b1)[c8 * 2];
        float4 bB = ((const float4*)b1)[c8 * 2 + 1];
        uint4 u;
        u.x = f2bf(fmaxf(a0 + bA.x, 0.f)) | (f2bf(fmaxf(a1 + bA.y, 0.f)) << 16);
        u.y = f2bf(fmaxf(a2 + bA.z, 0.f)) | (f2bf(fmaxf(a3 + bA.w, 0.f)) << 16);
        u.z = f2bf(fmaxf(a4 + bB.x, 0.f)) | (f2bf(fmaxf(a5 + bB.y, 0.f)) << 16);
        u.w = f2bf(fmaxf(a6 + bB.z, 0.f)) | (f2bf(fmaxf(a7 + bB.w, 0.f)) << 16);
        hb4[(size_t)node * 8 + c8] = u;
    }
}

// ---------------- gather conv2: bf16 rows (64 B), 16 edges in flight -------
__global__ __launch_bounds__(256) void gather32(const uint4* __restrict__ hwb4,
                                                const int* __restrict__ csr,
                                                const int* __restrict__ off,
                                                const float* __restrict__ dis,
                                                const float* __restrict__ bmu,
                                                const float* __restrict__ bls,
                                                float* __restrict__ out,
                                                int n_nodes) {
    int node = (blockIdx.x * 256 + threadIdx.x) >> 6;
    int lane = threadIdx.x & 63;
    if (node >= n_nodes) return;
    const int beg = off[node], end = off[node + 1];
    const float dn = dis[node];
    const int sub = lane >> 2;
    const int c4  = lane & 3;
    float a0 = 0.f, a1 = 0.f, a2 = 0.f, a3 = 0.f, a4 = 0.f, a5 = 0.f, a6 = 0.f, a7 = 0.f;
    for (int base = beg; base < end; base += 64) {
        const int cnt = min(64, end - base);
        int s = 0; float nrm = 0.f;
        if (lane < cnt) {
            s = __builtin_nontemporal_load(csr + base + lane);
            nrm = dis[s] * dn;
        }
        for (int j = 0; j < cnt; j += 16) {
            int jj = j + sub;
            int sj = __shfl(s, jj);
            float nj = __shfl(nrm, jj);
            if (jj < cnt) {
                uint4 r = hwb4[(size_t)sj * 4 + c4];
                a0 += bflo(r.x) * nj; a1 += bfhi(r.x) * nj;
                a2 += bflo(r.y) * nj; a3 += bfhi(r.y) * nj;
                a4 += bflo(r.z) * nj; a5 += bfhi(r.z) * nj;
                a6 += bflo(r.w) * nj; a7 += bfhi(r.w) * nj;
            }
        }
    }
    #pragma unroll
    for (int m = 4; m <= 32; m <<= 1) {
        a0 += __shfl_xor(a0, m); a1 += __shfl_xor(a1, m);
        a2 += __shfl_xor(a2, m); a3 += __shfl_xor(a3, m);
        a4 += __shfl_xor(a4, m); a5 += __shfl_xor(a5, m);
        a6 += __shfl_xor(a6, m); a7 += __shfl_xor(a7, m);
    }
    if (sub == 0) {
        uint4 r = hwb4[(size_t)node * 4 + c4];
        float s2 = dn * dn;
        a0 += bflo(r.x) * s2; a1 += bfhi(r.x) * s2;
        a2 += bflo(r.y) * s2; a3 += bfhi(r.y) * s2;
        a4 += bflo(r.z) * s2; a5 += bfhi(r.z) * s2;
        a6 += bflo(r.w) * s2; a7 += bfhi(r.w) * s2;
        const float4* bsrc = (c4 < 2) ? (const float4*)bmu : (const float4*)bls;
        int bi = (c4 & 1) * 2;
        float4 bA = bsrc[bi], bB = bsrc[bi + 1];
        float4 o1, o2;
        o1.x = a0 + bA.x; o1.y = a1 + bA.y; o1.z = a2 + bA.z; o1.w = a3 + bA.w;
        o2.x = a4 + bB.x; o2.y = a5 + bB.y; o2.z = a6 + bB.z; o2.w = a7 + bB.w;
        size_t rowbase = (c4 < 2) ? (size_t)node * 4 : ((size_t)n_nodes + node) * 4;
        ((float4*)out)[rowbase + (c4 & 1) * 2]     = o1;
        ((float4*)out)[rowbase + (c4 & 1) * 2 + 1] = o2;
    }
}

extern "C" void kernel_launch(void* const* d_in, const int* in_sizes, int n_in,
                              void* d_out, int out_size, void* d_ws, size_t ws_size,
                              hipStream_t stream) {
    const float* x   = (const float*)d_in[0];
    const int*   ei  = (const int*)d_in[1];
    const float* W1  = (const float*)d_in[2];
    const float* b1  = (const float*)d_in[3];
    const float* Wmu = (const float*)d_in[4];
    const float* bmu = (const float*)d_in[5];
    const float* Wls = (const float*)d_in[6];
    const float* bls = (const float*)d_in[7];
    float* out = (float*)d_out;

    const int N = in_sizes[0] / INC;       // 100000  (packing needs N < 2^17)
    const int E = in_sizes[1] / 2;         // 3200000
    const int* src = ei;
    const int* dst = ei + E;
    const int NBUCK = (N + 255) >> BSHIFT; // 391
    const int M = NBUCK * NBLK;            // 200192
    const int SBM = (M + 1023) / 1024;     // 196 (<=256 required)

    // workspace (4-byte words):
    //   dis [0,131072) | off [131072,262144)
    //   bcnt [262144,262144+M) | bofs [462336,462336+M) | partial/pbase [662528,..)
    //   csr [663040, 663040+E)
    //   xWb (N*32 uints) next | hb (N*32 uints) next; pairs aliases hb; hwb aliases xWb
    float* ws   = (float*)d_ws;
    float* dis  = ws;
    int*   off  = (int*)(ws + 131072);
    int*   bcnt = (int*)(ws + 262144);
    int*   bofs = (int*)(ws + 462336);
    int*   partial = (int*)(ws + 662528);
    int*   pbase   = partial + 256;
    int*   csr  = (int*)(ws + 663040);
    unsigned int* xWb = (unsigned int*)(ws + 663040 + (size_t)E);
    unsigned int* hb  = xWb + (size_t)N * 32;
    int*   pairs = (int*)hb;                     // dead before gather64 writes hb
    unsigned int* hwb = xWb;                     // xWb dead after gather64

    count_pass<<<NBLK, 256, 0, stream>>>(dst, bcnt, E, NBUCK);
    mscan_k1<<<SBM, 256, 0, stream>>>(bcnt, partial, M, NBUCK);
    mscan_k2<<<1, 256, 0, stream>>>(partial, pbase, SBM);
    mscan_k3<<<SBM, 256, 0, stream>>>(bcnt, pbase, bofs, M, NBUCK);
    place_pass<<<NBLK, 256, 0, stream>>>(src, dst, bofs, pairs, E, NBUCK);
    csr_bucket<<<NBUCK, 256, 0, stream>>>(pairs, bofs, off, dis, csr, N, E, NBUCK);

    gemm1_mfma<<<512, 256, 0, stream>>>(x, W1, xWb, N);
    gather64<<<(N * 64 + 255) / 256, 256, 0, stream>>>((const uint4*)xWb, (uint4*)hb,
                                                       csr, off, dis, b1, N);

    gemm2_mfma<<<512, 256, 0, stream>>>((const uint4*)hb, Wmu, Wls, hwb, N);
    gather32<<<(N * 64 + 255) / 256, 256, 0, stream>>>((const uint4*)hwb, csr, off, dis,
                                                       bmu, bls, out, N);
}

// Round 9
// 350.052 us; speedup vs baseline: 2.0731x; 1.0042x over previous
//
#include <hip/hip_runtime.h>
#include <hip/hip_bf16.h>

#define HIDC 64
#define INC 128
#define OUTC 16
#define NBLK 512            // blocks in count/place passes (must be pow2)
#define BSHIFT 8            // bucket = 256 nodes
#define MAXBUCK 512         // LDS array bound (nbuck=391 for N=100k)

typedef __attribute__((ext_vector_type(8))) short bf16x8;
typedef __attribute__((ext_vector_type(4))) float f32x4;

__device__ __forceinline__ float bflo(unsigned int u) {
    return __uint_as_float(u << 16);
}
__device__ __forceinline__ float bfhi(unsigned int u) {
    return __uint_as_float(u & 0xffff0000u);
}
__device__ __forceinline__ unsigned int f2bf(float f) {  // RNE to bf16 bits
    unsigned int b = __float_as_uint(f);
    return (b + 0x7fffu + ((b >> 16) & 1u)) >> 16;
}

// ---------------- pass A: per-(block,bucket) counts, no global atomics -----
__global__ __launch_bounds__(256) void count_pass(const int* __restrict__ dst,
                                                  int* __restrict__ bcnt,
                                                  int n_edges, int nbuck) {
    __shared__ int lh[MAXBUCK];
    for (int i = threadIdx.x; i < nbuck; i += 256) lh[i] = 0;
    __syncthreads();
    const int chunk = (n_edges + NBLK - 1) / NBLK;
    const int begin = blockIdx.x * chunk;
    const int end = min(begin + chunk, n_edges);
    for (int e = begin + threadIdx.x; e < end; e += 256) {
        int d = __builtin_nontemporal_load(dst + e);
        atomicAdd(&lh[d >> BSHIFT], 1);
    }
    __syncthreads();
    for (int i = threadIdx.x; i < nbuck; i += 256)
        bcnt[blockIdx.x * nbuck + i] = lh[i];
}

// logical j = bucket*NBLK + blk  ->  physical p = blk*nbuck + bucket
__device__ __forceinline__ int xphys(int j, int nbuck) {
    return (j & (NBLK - 1)) * nbuck + (j >> 9);
}

__global__ __launch_bounds__(256) void mscan_k1(const int* __restrict__ bcnt,
                                                int* __restrict__ partial,
                                                int m, int nbuck) {
    int base = blockIdx.x * 1024;
    int lim = min(base + 1024, m);
    int s = 0;
    for (int j = base + threadIdx.x; j < lim; j += 256) s += bcnt[xphys(j, nbuck)];
    #pragma unroll
    for (int d = 32; d; d >>= 1) s += __shfl_down(s, d);
    __shared__ int wsum[4];
    if ((threadIdx.x & 63) == 0) wsum[threadIdx.x >> 6] = s;
    __syncthreads();
    if (threadIdx.x == 0) partial[blockIdx.x] = wsum[0] + wsum[1] + wsum[2] + wsum[3];
}

__global__ __launch_bounds__(256) void mscan_k2(const int* __restrict__ partial,
                                                int* __restrict__ pbase, int nblk) {
    __shared__ int sh[256];
    int v = (threadIdx.x < nblk) ? partial[threadIdx.x] : 0;
    sh[threadIdx.x] = v;
    __syncthreads();
    for (int d = 1; d < 256; d <<= 1) {
        int t = (threadIdx.x >= d) ? sh[threadIdx.x - d] : 0;
        __syncthreads();
        sh[threadIdx.x] += t;
        __syncthreads();
    }
    if (threadIdx.x < nblk) pbase[threadIdx.x] = sh[threadIdx.x] - v;
}

__global__ __launch_bounds__(256) void mscan_k3(const int* __restrict__ bcnt,
                                                const int* __restrict__ pbase,
                                                int* __restrict__ bofs,
                                                int m, int nbuck) {
    int j0 = blockIdx.x * 1024 + threadIdx.x * 4;
    int c0 = (j0 + 0 < m) ? bcnt[xphys(j0 + 0, nbuck)] : 0;
    int c1 = (j0 + 1 < m) ? bcnt[xphys(j0 + 1, nbuck)] : 0;
    int c2 = (j0 + 2 < m) ? bcnt[xphys(j0 + 2, nbuck)] : 0;
    int c3 = (j0 + 3 < m) ? bcnt[xphys(j0 + 3, nbuck)] : 0;
    int tsum = c0 + c1 + c2 + c3;
    __shared__ int sh[256];
    sh[threadIdx.x] = tsum;
    __syncthreads();
    for (int d = 1; d < 256; d <<= 1) {
        int t = (threadIdx.x >= d) ? sh[threadIdx.x - d] : 0;
        __syncthreads();
        sh[threadIdx.x] += t;
        __syncthreads();
    }
    int pre = pbase[blockIdx.x] + sh[threadIdx.x] - tsum;
    if (j0 + 0 < m) bofs[xphys(j0 + 0, nbuck)] = pre;
    if (j0 + 1 < m) bofs[xphys(j0 + 1, nbuck)] = pre + c0;
    if (j0 + 2 < m) bofs[xphys(j0 + 2, nbuck)] = pre + c0 + c1;
    if (j0 + 3 < m) bofs[xphys(j0 + 3, nbuck)] = pre + c0 + c1 + c2;
}

// ---------------- pass B: deterministic placement, block-private cursors ---
__global__ __launch_bounds__(256) void place_pass(const int* __restrict__ src,
                                                  const int* __restrict__ dst,
                                                  const int* __restrict__ bofs,
                                                  int* __restrict__ pairs,
                                                  int n_edges, int nbuck) {
    __shared__ int lcur[MAXBUCK];
    for (int i = threadIdx.x; i < nbuck; i += 256)
        lcur[i] = bofs[blockIdx.x * nbuck + i];
    __syncthreads();
    const int chunk = (n_edges + NBLK - 1) / NBLK;
    const int begin = blockIdx.x * chunk;
    const int end = min(begin + chunk, n_edges);
    for (int e = begin + threadIdx.x; e < end; e += 256) {
        int d = __builtin_nontemporal_load(dst + e);
        int s = __builtin_nontemporal_load(src + e);
        int slot = atomicAdd(&lcur[d >> BSHIFT], 1);
        pairs[slot] = s | ((d & 255) << 17);
    }
}

// ---------------- pass C: per-bucket CSR + off + dis -----------------------
__global__ __launch_bounds__(256) void csr_bucket(const int* __restrict__ pairs,
                                                  const int* __restrict__ bofs,
                                                  int* __restrict__ off,
                                                  float* __restrict__ dis,
                                                  int* __restrict__ csr,
                                                  int n_nodes, int n_edges, int nbuck) {
    __shared__ int hist[256];
    __shared__ int lofs[256];
    __shared__ int ss[256];
    const int b = blockIdx.x;
    const int node0 = b << BSHIFT;
    const int nn = min(256, n_nodes - node0);
    const int pbeg = bofs[b];
    const int pend = (b + 1 < nbuck) ? bofs[b + 1] : n_edges;
    const int tid = threadIdx.x;
    hist[tid] = 0;
    __syncthreads();
    for (int i = pbeg + tid; i < pend; i += 256)
        atomicAdd(&hist[pairs[i] >> 17], 1);
    __syncthreads();
    int h0 = (tid < nn) ? hist[tid] : 0;
    ss[tid] = h0;
    __syncthreads();
    for (int d = 1; d < 256; d <<= 1) {
        int t = (tid >= d) ? ss[tid - d] : 0;
        __syncthreads();
        ss[tid] += t;
        __syncthreads();
    }
    int pre = pbeg + ss[tid] - h0;
    if (tid < nn) {
        lofs[tid] = pre;
        off[node0 + tid] = pre;
        dis[node0 + tid] = rsqrtf((float)(h0 + 1));
    }
    __syncthreads();
    for (int i = pbeg + tid; i < pend; i += 256) {
        int v = pairs[i];
        int slot = atomicAdd(&lofs[v >> 17], 1);
        csr[slot] = v & 0x1FFFF;
    }
    if (b == 0 && tid == 0) off[n_nodes] = n_edges;
}

// ---------------- GEMM 1 (MFMA): xWb = bf16( bf16(x) @ bf16(W1) ) ----------
__global__ __launch_bounds__(256) void gemm1_mfma(const float* __restrict__ x,
                                                  const float* __restrict__ W,
                                                  unsigned int* __restrict__ xWb,
                                                  int n_nodes) {
    __shared__ unsigned short WbT[64][136];
    __shared__ unsigned short xs[64][136];
    const int tid = threadIdx.x;
    const int lane = tid & 63, wave = tid >> 6;
    const int quad = lane >> 4, l16 = lane & 15;
    for (int i = tid; i < INC * HIDC; i += 256) {
        int k = i >> 6, n = i & 63;
        WbT[n][k] = (unsigned short)f2bf(W[i]);
    }
    __syncthreads();
    bf16x8 bfr[4][4];
    #pragma unroll
    for (int nt = 0; nt < 4; ++nt)
        #pragma unroll
        for (int kt = 0; kt < 4; ++kt)
            bfr[nt][kt] = *(const bf16x8*)&WbT[nt * 16 + l16][kt * 32 + quad * 8];

    for (int base = blockIdx.x * 64; base < n_nodes; base += gridDim.x * 64) {
        int nrows = min(64, n_nodes - base);
        __syncthreads();
        for (int i = tid; i < nrows * 32; i += 256) {
            int m = i >> 5, kq = i & 31;
            float4 v = ((const float4*)(x + (size_t)(base + m) * INC))[kq];
            unsigned int* xp = (unsigned int*)&xs[m][kq * 4];
            xp[0] = f2bf(v.x) | (f2bf(v.y) << 16);
            xp[1] = f2bf(v.z) | (f2bf(v.w) << 16);
        }
        __syncthreads();
        int mrow = wave * 16;
        if (mrow < nrows) {
            bf16x8 af[4];
            #pragma unroll
            for (int kt = 0; kt < 4; ++kt)
                af[kt] = *(const bf16x8*)&xs[mrow + l16][kt * 32 + quad * 8];
            f32x4 acc[4];
            #pragma unroll
            for (int nt = 0; nt < 4; ++nt) acc[nt] = (f32x4){0.f, 0.f, 0.f, 0.f};
            #pragma unroll
            for (int kt = 0; kt < 4; ++kt)
                #pragma unroll
                for (int nt = 0; nt < 4; ++nt)
                    acc[nt] = __builtin_amdgcn_mfma_f32_16x16x32_bf16(
                        af[kt], bfr[nt][kt], acc[nt], 0, 0, 0);
            #pragma unroll
            for (int nt = 0; nt < 4; ++nt) {
                #pragma unroll
                for (int r = 0; r < 4; ++r) {
                    unsigned int bv = f2bf(acc[nt][r]);
                    unsigned int hv = (unsigned int)__shfl_down((int)bv, 1);
                    int row = base + mrow + quad * 4 + r;
                    if (!(l16 & 1) && row < n_nodes)
                        xWb[((size_t)row * 64 + nt * 16 + l16) >> 1] = bv | (hv << 16);
                }
            }
        }
    }
}

// ---------------- GEMM 2 (MFMA): hwb = bf16( hb @ [W_mu|W_ls] ) ------------
__global__ __launch_bounds__(256) void gemm2_mfma(const uint4* __restrict__ hb4,
                                                  const float* __restrict__ Wmu,
                                                  const float* __restrict__ Wls,
                                                  unsigned int* __restrict__ hwb,
                                                  int n_nodes) {
    __shared__ unsigned short WT2[32][72];
    __shared__ unsigned short hs[64][72];
    const int tid = threadIdx.x;
    const int lane = tid & 63, wave = tid >> 6;
    const int quad = lane >> 4, l16 = lane & 15;
    for (int i = tid; i < HIDC * 32; i += 256) {
        int n = i & 31, k = i >> 5;
        float v = (n < 16) ? Wmu[k * 16 + n] : Wls[k * 16 + (n - 16)];
        WT2[n][k] = (unsigned short)f2bf(v);
    }
    __syncthreads();
    bf16x8 bfr[2][2];
    #pragma unroll
    for (int nt = 0; nt < 2; ++nt)
        #pragma unroll
        for (int kt = 0; kt < 2; ++kt)
            bfr[nt][kt] = *(const bf16x8*)&WT2[nt * 16 + l16][kt * 32 + quad * 8];

    for (int base = blockIdx.x * 64; base < n_nodes; base += gridDim.x * 64) {
        int nrows = min(64, n_nodes - base);
        __syncthreads();
        for (int i = tid; i < nrows * 8; i += 256) {
            int m = i >> 3, q = i & 7;
            uint4 v = hb4[(size_t)(base + m) * 8 + q];
            unsigned int* hp = (unsigned int*)&hs[m][q * 8];
            hp[0] = v.x; hp[1] = v.y; hp[2] = v.z; hp[3] = v.w;
        }
        __syncthreads();
        int mrow = wave * 16;
        if (mrow < nrows) {
            bf16x8 af[2];
            #pragma unroll
            for (int kt = 0; kt < 2; ++kt)
                af[kt] = *(const bf16x8*)&hs[mrow + l16][kt * 32 + quad * 8];
            f32x4 acc[2];
            #pragma unroll
            for (int nt = 0; nt < 2; ++nt) acc[nt] = (f32x4){0.f, 0.f, 0.f, 0.f};
            #pragma unroll
            for (int kt = 0; kt < 2; ++kt)
                #pragma unroll
                for (int nt = 0; nt < 2; ++nt)
                    acc[nt] = __builtin_amdgcn_mfma_f32_16x16x32_bf16(
                        af[kt], bfr[nt][kt], acc[nt], 0, 0, 0);
            #pragma unroll
            for (int nt = 0; nt < 2; ++nt) {
                #pragma unroll
                for (int r = 0; r < 4; ++r) {
                    unsigned int bv = f2bf(acc[nt][r]);
                    unsigned int hv = (unsigned int)__shfl_down((int)bv, 1);
                    int row = base + mrow + quad * 4 + r;
                    if (!(l16 & 1) && row < n_nodes)
                        hwb[((size_t)row * 32 + nt * 16 + l16) >> 1] = bv | (hv << 16);
                }
            }
        }
    }
}

// ---------------- gather conv1 v2: 16 lanes per node, lane owns 4 channels -
// No cross-lane reduce, no shfl staging: csr/dis loads are same-address
// broadcasts within the 16-lane group; rows loaded as uint2 (4 bf16)/lane.
__global__ __launch_bounds__(256) void gather64(const uint2* __restrict__ xWb2,
                                                uint2* __restrict__ hb2,
                                                const int* __restrict__ csr,
                                                const int* __restrict__ off,
                                                const float* __restrict__ dis,
                                                const float* __restrict__ b1,
                                                int n_nodes) {
    const int tid = threadIdx.x;
    const int lane = tid & 63;
    const int grp = lane >> 4;          // 4 nodes per wave
    const int l16 = lane & 15;          // channel quad
    int node = blockIdx.x * 16 + (tid >> 6) * 4 + grp;
    int beg = 0, end = 0;
    float dn = 0.f;
    if (node < n_nodes) {
        beg = off[node];
        end = off[node + 1];
        dn = dis[node];
    }
    float a0 = 0.f, a1 = 0.f, a2 = 0.f, a3 = 0.f;
    int e = beg;
    for (; e + 2 <= end; e += 2) {
        int s0 = csr[e], s1 = csr[e + 1];
        float n0 = dis[s0] * dn, n1 = dis[s1] * dn;
        uint2 r0 = xWb2[(size_t)s0 * 16 + l16];
        uint2 r1 = xWb2[(size_t)s1 * 16 + l16];
        a0 += bflo(r0.x) * n0; a1 += bfhi(r0.x) * n0;
        a2 += bflo(r0.y) * n0; a3 += bfhi(r0.y) * n0;
        a0 += bflo(r1.x) * n1; a1 += bfhi(r1.x) * n1;
        a2 += bflo(r1.y) * n1; a3 += bfhi(r1.y) * n1;
    }
    if (e < end) {
        int s0 = csr[e];
        float n0 = dis[s0] * dn;
        uint2 r0 = xWb2[(size_t)s0 * 16 + l16];
        a0 += bflo(r0.x) * n0; a1 += bfhi(r0.x) * n0;
        a2 += bflo(r0.y) * n0; a3 += bfhi(r0.y) * n0;
    }
    if (node < n_nodes) {
        uint2 r = xWb2[(size_t)node * 16 + l16];
        float s2 = dn * dn;
        a0 += bflo(r.x) * s2; a1 += bfhi(r.x) * s2;
        a2 += bflo(r.y) * s2; a3 += bfhi(r.y) * s2;
        float4 b = ((const float4*)b1)[l16];
        uint2 u;
        u.x = f2bf(fmaxf(a0 + b.x, 0.f)) | (f2bf(fmaxf(a1 + b.y, 0.f)) << 16);
        u.y = f2bf(fmaxf(a2 + b.z, 0.f)) | (f2bf(fmaxf(a3 + b.w, 0.f)) << 16);
        hb2[(size_t)node * 16 + l16] = u;
    }
}

// ---------------- gather conv2 v2: 8 lanes per node, lane owns 4 channels --
__global__ __launch_bounds__(256) void gather32(const uint2* __restrict__ hwb2,
                                                const int* __restrict__ csr,
                                                const int* __restrict__ off,
                                                const float* __restrict__ dis,
                                                const float* __restrict__ bmu,
                                                const float* __restrict__ bls,
                                                float* __restrict__ out,
                                                int n_nodes) {
    const int tid = threadIdx.x;
    const int lane = tid & 63;
    const int grp = lane >> 3;          // 8 nodes per wave
    const int l8 = lane & 7;            // channel quad
    int node = blockIdx.x * 32 + (tid >> 6) * 8 + grp;
    int beg = 0, end = 0;
    float dn = 0.f;
    if (node < n_nodes) {
        beg = off[node];
        end = off[node + 1];
        dn = dis[node];
    }
    float a0 = 0.f, a1 = 0.f, a2 = 0.f, a3 = 0.f;
    int e = beg;
    for (; e + 2 <= end; e += 2) {
        int s0 = csr[e], s1 = csr[e + 1];
        float n0 = dis[s0] * dn, n1 = dis[s1] * dn;
        uint2 r0 = hwb2[(size_t)s0 * 8 + l8];
        uint2 r1 = hwb2[(size_t)s1 * 8 + l8];
        a0 += bflo(r0.x) * n0; a1 += bfhi(r0.x) * n0;
        a2 += bflo(r0.y) * n0; a3 += bfhi(r0.y) * n0;
        a0 += bflo(r1.x) * n1; a1 += bfhi(r1.x) * n1;
        a2 += bflo(r1.y) * n1; a3 += bfhi(r1.y) * n1;
    }
    if (e < end) {
        int s0 = csr[e];
        float n0 = dis[s0] * dn;
        uint2 r0 = hwb2[(size_t)s0 * 8 + l8];
        a0 += bflo(r0.x) * n0; a1 += bfhi(r0.x) * n0;
        a2 += bflo(r0.y) * n0; a3 += bfhi(r0.y) * n0;
    }
    if (node < n_nodes) {
        uint2 r = hwb2[(size_t)node * 8 + l8];
        float s2 = dn * dn;
        a0 += bflo(r.x) * s2; a1 += bfhi(r.x) * s2;
        a2 += bflo(r.y) * s2; a3 += bfhi(r.y) * s2;
        float4 b = (l8 < 4) ? ((const float4*)bmu)[l8] : ((const float4*)bls)[l8 - 4];
        float4 o;
        o.x = a0 + b.x; o.y = a1 + b.y; o.z = a2 + b.z; o.w = a3 + b.w;
        if (l8 < 4)
            ((float4*)out)[(size_t)node * 4 + l8] = o;
        else
            ((float4*)out)[((size_t)n_nodes + node) * 4 + (l8 - 4)] = o;
    }
}

extern "C" void kernel_launch(void* const* d_in, const int* in_sizes, int n_in,
                              void* d_out, int out_size, void* d_ws, size_t ws_size,
                              hipStream_t stream) {
    const float* x   = (const float*)d_in[0];
    const int*   ei  = (const int*)d_in[1];
    const float* W1  = (const float*)d_in[2];
    const float* b1  = (const float*)d_in[3];
    const float* Wmu = (const float*)d_in[4];
    const float* bmu = (const float*)d_in[5];
    const float* Wls = (const float*)d_in[6];
    const float* bls = (const float*)d_in[7];
    float* out = (float*)d_out;

    const int N = in_sizes[0] / INC;       // 100000  (packing needs N < 2^17)
    const int E = in_sizes[1] / 2;         // 3200000
    const int* src = ei;
    const int* dst = ei + E;
    const int NBUCK = (N + 255) >> BSHIFT; // 391
    const int M = NBUCK * NBLK;            // 200192
    const int SBM = (M + 1023) / 1024;     // 196 (<=256 required)

    float* ws   = (float*)d_ws;
    float* dis  = ws;
    int*   off  = (int*)(ws + 131072);
    int*   bcnt = (int*)(ws + 262144);
    int*   bofs = (int*)(ws + 462336);
    int*   partial = (int*)(ws + 662528);
    int*   pbase   = partial + 256;
    int*   csr  = (int*)(ws + 663040);
    unsigned int* xWb = (unsigned int*)(ws + 663040 + (size_t)E);
    unsigned int* hb  = xWb + (size_t)N * 32;
    int*   pairs = (int*)hb;                     // dead before gather64 writes hb
    unsigned int* hwb = xWb;                     // xWb dead after gather64

    count_pass<<<NBLK, 256, 0, stream>>>(dst, bcnt, E, NBUCK);
    mscan_k1<<<SBM, 256, 0, stream>>>(bcnt, partial, M, NBUCK);
    mscan_k2<<<1, 256, 0, stream>>>(partial, pbase, SBM);
    mscan_k3<<<SBM, 256, 0, stream>>>(bcnt, pbase, bofs, M, NBUCK);
    place_pass<<<NBLK, 256, 0, stream>>>(src, dst, bofs, pairs, E, NBUCK);
    csr_bucket<<<NBUCK, 256, 0, stream>>>(pairs, bofs, off, dis, csr, N, E, NBUCK);

    gemm1_mfma<<<512, 256, 0, stream>>>(x, W1, xWb, N);
    gather64<<<(N + 15) / 16, 256, 0, stream>>>((const uint2*)xWb, (uint2*)hb,
                                                csr, off, dis, b1, N);

    gemm2_mfma<<<512, 256, 0, stream>>>((const uint4*)hb, Wmu, Wls, hwb, N);
    gather32<<<(N + 31) / 32, 256, 0, stream>>>((const uint2*)hwb, csr, off, dis,
                                                bmu, bls, out, N);
}

// Round 10
// 338.313 us; speedup vs baseline: 2.1450x; 1.0347x over previous
//
#include <hip/hip_runtime.h>
#include <hip/hip_bf16.h>

#define HIDC 64
#define INC 128
#define OUTC 16
#define NBLK 512            // blocks in count/place passes (must be pow2)
#define BSHIFT 8            // bucket = 256 nodes
#define MAXBUCK 512         // LDS array bound (nbuck=391 for N=100k)

typedef __attribute__((ext_vector_type(8))) short bf16x8;
typedef __attribute__((ext_vector_type(4))) float f32x4;

__device__ __forceinline__ float bflo(unsigned int u) {
    return __uint_as_float(u << 16);
}
__device__ __forceinline__ float bfhi(unsigned int u) {
    return __uint_as_float(u & 0xffff0000u);
}
__device__ __forceinline__ unsigned int f2bf(float f) {  // RNE to bf16 bits
    unsigned int b = __float_as_uint(f);
    return (b + 0x7fffu + ((b >> 16) & 1u)) >> 16;
}

// ---------------- pass A: per-(block,bucket) counts, no global atomics -----
__global__ __launch_bounds__(256) void count_pass(const int* __restrict__ dst,
                                                  int* __restrict__ bcnt,
                                                  int n_edges, int nbuck) {
    __shared__ int lh[MAXBUCK];
    for (int i = threadIdx.x; i < nbuck; i += 256) lh[i] = 0;
    __syncthreads();
    const int chunk = (n_edges + NBLK - 1) / NBLK;
    const int begin = blockIdx.x * chunk;
    const int end = min(begin + chunk, n_edges);
    for (int e = begin + threadIdx.x; e < end; e += 256) {
        int d = __builtin_nontemporal_load(dst + e);
        atomicAdd(&lh[d >> BSHIFT], 1);
    }
    __syncthreads();
    for (int i = threadIdx.x; i < nbuck; i += 256)
        bcnt[blockIdx.x * nbuck + i] = lh[i];
}

// logical j = bucket*NBLK + blk  ->  physical p = blk*nbuck + bucket
__device__ __forceinline__ int xphys(int j, int nbuck) {
    return (j & (NBLK - 1)) * nbuck + (j >> 9);
}

__global__ __launch_bounds__(256) void mscan_k1(const int* __restrict__ bcnt,
                                                int* __restrict__ partial,
                                                int m, int nbuck) {
    int base = blockIdx.x * 1024;
    int lim = min(base + 1024, m);
    int s = 0;
    for (int j = base + threadIdx.x; j < lim; j += 256) s += bcnt[xphys(j, nbuck)];
    #pragma unroll
    for (int d = 32; d; d >>= 1) s += __shfl_down(s, d);
    __shared__ int wsum[4];
    if ((threadIdx.x & 63) == 0) wsum[threadIdx.x >> 6] = s;
    __syncthreads();
    if (threadIdx.x == 0) partial[blockIdx.x] = wsum[0] + wsum[1] + wsum[2] + wsum[3];
}

__global__ __launch_bounds__(256) void mscan_k2(const int* __restrict__ partial,
                                                int* __restrict__ pbase, int nblk) {
    __shared__ int sh[256];
    int v = (threadIdx.x < nblk) ? partial[threadIdx.x] : 0;
    sh[threadIdx.x] = v;
    __syncthreads();
    for (int d = 1; d < 256; d <<= 1) {
        int t = (threadIdx.x >= d) ? sh[threadIdx.x - d] : 0;
        __syncthreads();
        sh[threadIdx.x] += t;
        __syncthreads();
    }
    if (threadIdx.x < nblk) pbase[threadIdx.x] = sh[threadIdx.x] - v;
}

__global__ __launch_bounds__(256) void mscan_k3(const int* __restrict__ bcnt,
                                                const int* __restrict__ pbase,
                                                int* __restrict__ bofs,
                                                int m, int nbuck) {
    int j0 = blockIdx.x * 1024 + threadIdx.x * 4;
    int c0 = (j0 + 0 < m) ? bcnt[xphys(j0 + 0, nbuck)] : 0;
    int c1 = (j0 + 1 < m) ? bcnt[xphys(j0 + 1, nbuck)] : 0;
    int c2 = (j0 + 2 < m) ? bcnt[xphys(j0 + 2, nbuck)] : 0;
    int c3 = (j0 + 3 < m) ? bcnt[xphys(j0 + 3, nbuck)] : 0;
    int tsum = c0 + c1 + c2 + c3;
    __shared__ int sh[256];
    sh[threadIdx.x] = tsum;
    __syncthreads();
    for (int d = 1; d < 256; d <<= 1) {
        int t = (threadIdx.x >= d) ? sh[threadIdx.x - d] : 0;
        __syncthreads();
        sh[threadIdx.x] += t;
        __syncthreads();
    }
    int pre = pbase[blockIdx.x] + sh[threadIdx.x] - tsum;
    if (j0 + 0 < m) bofs[xphys(j0 + 0, nbuck)] = pre;
    if (j0 + 1 < m) bofs[xphys(j0 + 1, nbuck)] = pre + c0;
    if (j0 + 2 < m) bofs[xphys(j0 + 2, nbuck)] = pre + c0 + c1;
    if (j0 + 3 < m) bofs[xphys(j0 + 3, nbuck)] = pre + c0 + c1 + c2;
}

// ---------------- pass B: deterministic placement, block-private cursors ---
__global__ __launch_bounds__(256) void place_pass(const int* __restrict__ src,
                                                  const int* __restrict__ dst,
                                                  const int* __restrict__ bofs,
                                                  int* __restrict__ pairs,
                                                  int n_edges, int nbuck) {
    __shared__ int lcur[MAXBUCK];
    for (int i = threadIdx.x; i < nbuck; i += 256)
        lcur[i] = bofs[blockIdx.x * nbuck + i];
    __syncthreads();
    const int chunk = (n_edges + NBLK - 1) / NBLK;
    const int begin = blockIdx.x * chunk;
    const int end = min(begin + chunk, n_edges);
    for (int e = begin + threadIdx.x; e < end; e += 256) {
        int d = __builtin_nontemporal_load(dst + e);
        int s = __builtin_nontemporal_load(src + e);
        int slot = atomicAdd(&lcur[d >> BSHIFT], 1);
        pairs[slot] = s | ((d & 255) << 17);
    }
}

// ---------------- pass C: per-bucket CSR + off + dis -----------------------
__global__ __launch_bounds__(256) void csr_bucket(const int* __restrict__ pairs,
                                                  const int* __restrict__ bofs,
                                                  int* __restrict__ off,
                                                  float* __restrict__ dis,
                                                  int* __restrict__ csr,
                                                  int n_nodes, int n_edges, int nbuck) {
    __shared__ int hist[256];
    __shared__ int lofs[256];
    __shared__ int ss[256];
    const int b = blockIdx.x;
    const int node0 = b << BSHIFT;
    const int nn = min(256, n_nodes - node0);
    const int pbeg = bofs[b];
    const int pend = (b + 1 < nbuck) ? bofs[b + 1] : n_edges;
    const int tid = threadIdx.x;
    hist[tid] = 0;
    __syncthreads();
    for (int i = pbeg + tid; i < pend; i += 256)
        atomicAdd(&hist[pairs[i] >> 17], 1);
    __syncthreads();
    int h0 = (tid < nn) ? hist[tid] : 0;
    ss[tid] = h0;
    __syncthreads();
    for (int d = 1; d < 256; d <<= 1) {
        int t = (tid >= d) ? ss[tid - d] : 0;
        __syncthreads();
        ss[tid] += t;
        __syncthreads();
    }
    int pre = pbeg + ss[tid] - h0;
    if (tid < nn) {
        lofs[tid] = pre;
        off[node0 + tid] = pre;
        dis[node0 + tid] = rsqrtf((float)(h0 + 1));
    }
    __syncthreads();
    for (int i = pbeg + tid; i < pend; i += 256) {
        int v = pairs[i];
        int slot = atomicAdd(&lofs[v >> 17], 1);
        csr[slot] = v & 0x1FFFF;
    }
    if (b == 0 && tid == 0) off[n_nodes] = n_edges;
}

// ---------------- pass D: pack q15(dis[s]) into csr high bits --------------
// csr[e] = s | (q15 << 17), q15 = round(dis[s]*32767), dis in (0,1].
// Removes the per-edge random dis load (and its latency hop) from both gathers.
__global__ __launch_bounds__(256) void pack_norm(int* __restrict__ csr,
                                                 const float* __restrict__ dis,
                                                 int n_edges) {
    int e = blockIdx.x * 256 + threadIdx.x;
    if (e < n_edges) {
        int s = csr[e];
        int q = (int)(dis[s] * 32767.f + 0.5f);
        csr[e] = s | (q << 17);
    }
}

// ---------------- GEMM 1 (MFMA): xWb = bf16( bf16(x) @ bf16(W1) ) ----------
__global__ __launch_bounds__(256) void gemm1_mfma(const float* __restrict__ x,
                                                  const float* __restrict__ W,
                                                  unsigned int* __restrict__ xWb,
                                                  int n_nodes) {
    __shared__ unsigned short WbT[64][136];
    __shared__ unsigned short xs[64][136];
    const int tid = threadIdx.x;
    const int lane = tid & 63, wave = tid >> 6;
    const int quad = lane >> 4, l16 = lane & 15;
    for (int i = tid; i < INC * HIDC; i += 256) {
        int k = i >> 6, n = i & 63;
        WbT[n][k] = (unsigned short)f2bf(W[i]);
    }
    __syncthreads();
    bf16x8 bfr[4][4];
    #pragma unroll
    for (int nt = 0; nt < 4; ++nt)
        #pragma unroll
        for (int kt = 0; kt < 4; ++kt)
            bfr[nt][kt] = *(const bf16x8*)&WbT[nt * 16 + l16][kt * 32 + quad * 8];

    for (int base = blockIdx.x * 64; base < n_nodes; base += gridDim.x * 64) {
        int nrows = min(64, n_nodes - base);
        __syncthreads();
        for (int i = tid; i < nrows * 32; i += 256) {
            int m = i >> 5, kq = i & 31;
            float4 v = ((const float4*)(x + (size_t)(base + m) * INC))[kq];
            unsigned int* xp = (unsigned int*)&xs[m][kq * 4];
            xp[0] = f2bf(v.x) | (f2bf(v.y) << 16);
            xp[1] = f2bf(v.z) | (f2bf(v.w) << 16);
        }
        __syncthreads();
        int mrow = wave * 16;
        if (mrow < nrows) {
            bf16x8 af[4];
            #pragma unroll
            for (int kt = 0; kt < 4; ++kt)
                af[kt] = *(const bf16x8*)&xs[mrow + l16][kt * 32 + quad * 8];
            f32x4 acc[4];
            #pragma unroll
            for (int nt = 0; nt < 4; ++nt) acc[nt] = (f32x4){0.f, 0.f, 0.f, 0.f};
            #pragma unroll
            for (int kt = 0; kt < 4; ++kt)
                #pragma unroll
                for (int nt = 0; nt < 4; ++nt)
                    acc[nt] = __builtin_amdgcn_mfma_f32_16x16x32_bf16(
                        af[kt], bfr[nt][kt], acc[nt], 0, 0, 0);
            #pragma unroll
            for (int nt = 0; nt < 4; ++nt) {
                #pragma unroll
                for (int r = 0; r < 4; ++r) {
                    unsigned int bv = f2bf(acc[nt][r]);
                    unsigned int hv = (unsigned int)__shfl_down((int)bv, 1);
                    int row = base + mrow + quad * 4 + r;
                    if (!(l16 & 1) && row < n_nodes)
                        xWb[((size_t)row * 64 + nt * 16 + l16) >> 1] = bv | (hv << 16);
                }
            }
        }
    }
}

// ---------------- GEMM 2 (MFMA): hwb = bf16( hb @ [W_mu|W_ls] ) ------------
__global__ __launch_bounds__(256) void gemm2_mfma(const uint4* __restrict__ hb4,
                                                  const float* __restrict__ Wmu,
                                                  const float* __restrict__ Wls,
                                                  unsigned int* __restrict__ hwb,
                                                  int n_nodes) {
    __shared__ unsigned short WT2[32][72];
    __shared__ unsigned short hs[64][72];
    const int tid = threadIdx.x;
    const int lane = tid & 63, wave = tid >> 6;
    const int quad = lane >> 4, l16 = lane & 15;
    for (int i = tid; i < HIDC * 32; i += 256) {
        int n = i & 31, k = i >> 5;
        float v = (n < 16) ? Wmu[k * 16 + n] : Wls[k * 16 + (n - 16)];
        WT2[n][k] = (unsigned short)f2bf(v);
    }
    __syncthreads();
    bf16x8 bfr[2][2];
    #pragma unroll
    for (int nt = 0; nt < 2; ++nt)
        #pragma unroll
        for (int kt = 0; kt < 2; ++kt)
            bfr[nt][kt] = *(const bf16x8*)&WT2[nt * 16 + l16][kt * 32 + quad * 8];

    for (int base = blockIdx.x * 64; base < n_nodes; base += gridDim.x * 64) {
        int nrows = min(64, n_nodes - base);
        __syncthreads();
        for (int i = tid; i < nrows * 8; i += 256) {
            int m = i >> 3, q = i & 7;
            uint4 v = hb4[(size_t)(base + m) * 8 + q];
            unsigned int* hp = (unsigned int*)&hs[m][q * 8];
            hp[0] = v.x; hp[1] = v.y; hp[2] = v.z; hp[3] = v.w;
        }
        __syncthreads();
        int mrow = wave * 16;
        if (mrow < nrows) {
            bf16x8 af[2];
            #pragma unroll
            for (int kt = 0; kt < 2; ++kt)
                af[kt] = *(const bf16x8*)&hs[mrow + l16][kt * 32 + quad * 8];
            f32x4 acc[2];
            #pragma unroll
            for (int nt = 0; nt < 2; ++nt) acc[nt] = (f32x4){0.f, 0.f, 0.f, 0.f};
            #pragma unroll
            for (int kt = 0; kt < 2; ++kt)
                #pragma unroll
                for (int nt = 0; nt < 2; ++nt)
                    acc[nt] = __builtin_amdgcn_mfma_f32_16x16x32_bf16(
                        af[kt], bfr[nt][kt], acc[nt], 0, 0, 0);
            #pragma unroll
            for (int nt = 0; nt < 2; ++nt) {
                #pragma unroll
                for (int r = 0; r < 4; ++r) {
                    unsigned int bv = f2bf(acc[nt][r]);
                    unsigned int hv = (unsigned int)__shfl_down((int)bv, 1);
                    int row = base + mrow + quad * 4 + r;
                    if (!(l16 & 1) && row < n_nodes)
                        hwb[((size_t)row * 32 + nt * 16 + l16) >> 1] = bv | (hv << 16);
                }
            }
        }
    }
}

// ---------------- gather conv1 v3: 16 lanes/node, q15 norm in csr, unroll 4
__global__ __launch_bounds__(256) void gather64(const uint2* __restrict__ xWb2,
                                                uint2* __restrict__ hb2,
                                                const int* __restrict__ csr,
                                                const int* __restrict__ off,
                                                const float* __restrict__ dis,
                                                const float* __restrict__ b1,
                                                int n_nodes) {
    const int tid = threadIdx.x;
    const int lane = tid & 63;
    const int grp = lane >> 4;          // 4 nodes per wave
    const int l16 = lane & 15;          // channel quad
    int node = blockIdx.x * 16 + (tid >> 6) * 4 + grp;
    if (node >= n_nodes) return;        // no barriers/cross-lane below: safe
    const int beg = off[node], end = off[node + 1];
    const float dn = dis[node];
    const float dnq = dn * (1.0f / 32767.0f);
    float a0 = 0.f, a1 = 0.f, a2 = 0.f, a3 = 0.f;
    int e = beg;
    for (; e + 4 <= end; e += 4) {
        unsigned int v0 = (unsigned int)csr[e];
        unsigned int v1 = (unsigned int)csr[e + 1];
        unsigned int v2 = (unsigned int)csr[e + 2];
        unsigned int v3 = (unsigned int)csr[e + 3];
        uint2 r0 = xWb2[(size_t)(v0 & 0x1FFFF) * 16 + l16];
        uint2 r1 = xWb2[(size_t)(v1 & 0x1FFFF) * 16 + l16];
        uint2 r2 = xWb2[(size_t)(v2 & 0x1FFFF) * 16 + l16];
        uint2 r3 = xWb2[(size_t)(v3 & 0x1FFFF) * 16 + l16];
        float n0 = (float)(v0 >> 17) * dnq;
        float n1 = (float)(v1 >> 17) * dnq;
        float n2 = (float)(v2 >> 17) * dnq;
        float n3 = (float)(v3 >> 17) * dnq;
        a0 += bflo(r0.x) * n0; a1 += bfhi(r0.x) * n0;
        a2 += bflo(r0.y) * n0; a3 += bfhi(r0.y) * n0;
        a0 += bflo(r1.x) * n1; a1 += bfhi(r1.x) * n1;
        a2 += bflo(r1.y) * n1; a3 += bfhi(r1.y) * n1;
        a0 += bflo(r2.x) * n2; a1 += bfhi(r2.x) * n2;
        a2 += bflo(r2.y) * n2; a3 += bfhi(r2.y) * n2;
        a0 += bflo(r3.x) * n3; a1 += bfhi(r3.x) * n3;
        a2 += bflo(r3.y) * n3; a3 += bfhi(r3.y) * n3;
    }
    for (; e < end; ++e) {
        unsigned int v0 = (unsigned int)csr[e];
        uint2 r0 = xWb2[(size_t)(v0 & 0x1FFFF) * 16 + l16];
        float n0 = (float)(v0 >> 17) * dnq;
        a0 += bflo(r0.x) * n0; a1 += bfhi(r0.x) * n0;
        a2 += bflo(r0.y) * n0; a3 += bfhi(r0.y) * n0;
    }
    {
        uint2 r = xWb2[(size_t)node * 16 + l16];
        float s2 = dn * dn;
        a0 += bflo(r.x) * s2; a1 += bfhi(r.x) * s2;
        a2 += bflo(r.y) * s2; a3 += bfhi(r.y) * s2;
        float4 b = ((const float4*)b1)[l16];
        uint2 u;
        u.x = f2bf(fmaxf(a0 + b.x, 0.f)) | (f2bf(fmaxf(a1 + b.y, 0.f)) << 16);
        u.y = f2bf(fmaxf(a2 + b.z, 0.f)) | (f2bf(fmaxf(a3 + b.w, 0.f)) << 16);
        hb2[(size_t)node * 16 + l16] = u;
    }
}

// ---------------- gather conv2 v3: 8 lanes/node, q15 norm, unroll 4 --------
__global__ __launch_bounds__(256) void gather32(const uint2* __restrict__ hwb2,
                                                const int* __restrict__ csr,
                                                const int* __restrict__ off,
                                                const float* __restrict__ dis,
                                                const float* __restrict__ bmu,
                                                const float* __restrict__ bls,
                                                float* __restrict__ out,
                                                int n_nodes) {
    const int tid = threadIdx.x;
    const int lane = tid & 63;
    const int grp = lane >> 3;          // 8 nodes per wave
    const int l8 = lane & 7;            // channel quad
    int node = blockIdx.x * 32 + (tid >> 6) * 8 + grp;
    if (node >= n_nodes) return;
    const int beg = off[node], end = off[node + 1];
    const float dn = dis[node];
    const float dnq = dn * (1.0f / 32767.0f);
    float a0 = 0.f, a1 = 0.f, a2 = 0.f, a3 = 0.f;
    int e = beg;
    for (; e + 4 <= end; e += 4) {
        unsigned int v0 = (unsigned int)csr[e];
        unsigned int v1 = (unsigned int)csr[e + 1];
        unsigned int v2 = (unsigned int)csr[e + 2];
        unsigned int v3 = (unsigned int)csr[e + 3];
        uint2 r0 = hwb2[(size_t)(v0 & 0x1FFFF) * 8 + l8];
        uint2 r1 = hwb2[(size_t)(v1 & 0x1FFFF) * 8 + l8];
        uint2 r2 = hwb2[(size_t)(v2 & 0x1FFFF) * 8 + l8];
        uint2 r3 = hwb2[(size_t)(v3 & 0x1FFFF) * 8 + l8];
        float n0 = (float)(v0 >> 17) * dnq;
        float n1 = (float)(v1 >> 17) * dnq;
        float n2 = (float)(v2 >> 17) * dnq;
        float n3 = (float)(v3 >> 17) * dnq;
        a0 += bflo(r0.x) * n0; a1 += bfhi(r0.x) * n0;
        a2 += bflo(r0.y) * n0; a3 += bfhi(r0.y) * n0;
        a0 += bflo(r1.x) * n1; a1 += bfhi(r1.x) * n1;
        a2 += bflo(r1.y) * n1; a3 += bfhi(r1.y) * n1;
        a0 += bflo(r2.x) * n2; a1 += bfhi(r2.x) * n2;
        a2 += bflo(r2.y) * n2; a3 += bfhi(r2.y) * n2;
        a0 += bflo(r3.x) * n3; a1 += bfhi(r3.x) * n3;
        a2 += bflo(r3.y) * n3; a3 += bfhi(r3.y) * n3;
    }
    for (; e < end; ++e) {
        unsigned int v0 = (unsigned int)csr[e];
        uint2 r0 = hwb2[(size_t)(v0 & 0x1FFFF) * 8 + l8];
        float n0 = (float)(v0 >> 17) * dnq;
        a0 += bflo(r0.x) * n0; a1 += bfhi(r0.x) * n0;
        a2 += bflo(r0.y) * n0; a3 += bfhi(r0.y) * n0;
    }
    {
        uint2 r = hwb2[(size_t)node * 8 + l8];
        float s2 = dn * dn;
        a0 += bflo(r.x) * s2; a1 += bfhi(r.x) * s2;
        a2 += bflo(r.y) * s2; a3 += bfhi(r.y) * s2;
        float4 b = (l8 < 4) ? ((const float4*)bmu)[l8] : ((const float4*)bls)[l8 - 4];
        float4 o;
        o.x = a0 + b.x; o.y = a1 + b.y; o.z = a2 + b.z; o.w = a3 + b.w;
        if (l8 < 4)
            ((float4*)out)[(size_t)node * 4 + l8] = o;
        else
            ((float4*)out)[((size_t)n_nodes + node) * 4 + (l8 - 4)] = o;
    }
}

extern "C" void kernel_launch(void* const* d_in, const int* in_sizes, int n_in,
                              void* d_out, int out_size, void* d_ws, size_t ws_size,
                              hipStream_t stream) {
    const float* x   = (const float*)d_in[0];
    const int*   ei  = (const int*)d_in[1];
    const float* W1  = (const float*)d_in[2];
    const float* b1  = (const float*)d_in[3];
    const float* Wmu = (const float*)d_in[4];
    const float* bmu = (const float*)d_in[5];
    const float* Wls = (const float*)d_in[6];
    const float* bls = (const float*)d_in[7];
    float* out = (float*)d_out;

    const int N = in_sizes[0] / INC;       // 100000  (packing needs N < 2^17)
    const int E = in_sizes[1] / 2;         // 3200000
    const int* src = ei;
    const int* dst = ei + E;
    const int NBUCK = (N + 255) >> BSHIFT; // 391
    const int M = NBUCK * NBLK;            // 200192
    const int SBM = (M + 1023) / 1024;     // 196 (<=256 required)

    float* ws   = (float*)d_ws;
    float* dis  = ws;
    int*   off  = (int*)(ws + 131072);
    int*   bcnt = (int*)(ws + 262144);
    int*   bofs = (int*)(ws + 462336);
    int*   partial = (int*)(ws + 662528);
    int*   pbase   = partial + 256;
    int*   csr  = (int*)(ws + 663040);
    unsigned int* xWb = (unsigned int*)(ws + 663040 + (size_t)E);
    unsigned int* hb  = xWb + (size_t)N * 32;
    int*   pairs = (int*)hb;                     // dead before gather64 writes hb
    unsigned int* hwb = xWb;                     // xWb dead after gather64

    count_pass<<<NBLK, 256, 0, stream>>>(dst, bcnt, E, NBUCK);
    mscan_k1<<<SBM, 256, 0, stream>>>(bcnt, partial, M, NBUCK);
    mscan_k2<<<1, 256, 0, stream>>>(partial, pbase, SBM);
    mscan_k3<<<SBM, 256, 0, stream>>>(bcnt, pbase, bofs, M, NBUCK);
    place_pass<<<NBLK, 256, 0, stream>>>(src, dst, bofs, pairs, E, NBUCK);
    csr_bucket<<<NBUCK, 256, 0, stream>>>(pairs, bofs, off, dis, csr, N, E, NBUCK);
    pack_norm<<<(E + 255) / 256, 256, 0, stream>>>(csr, dis, E);

    gemm1_mfma<<<512, 256, 0, stream>>>(x, W1, xWb, N);
    gather64<<<(N + 15) / 16, 256, 0, stream>>>((const uint2*)xWb, (uint2*)hb,
                                                csr, off, dis, b1, N);

    gemm2_mfma<<<512, 256, 0, stream>>>((const uint4*)hb, Wmu, Wls, hwb, N);
    gather32<<<(N + 31) / 32, 256, 0, stream>>>((const uint2*)hwb, csr, off, dis,
                                                bmu, bls, out, N);
}